// Round 1
// 1314.323 us; speedup vs baseline: 1.3099x; 1.3099x over previous
//
#include <hip/hip_runtime.h>
#include <stdint.h>

typedef unsigned short u16;
typedef __bf16 bf16x8 __attribute__((ext_vector_type(8)));
typedef float f32x4 __attribute__((ext_vector_type(4)));

__device__ __forceinline__ float b2f(u16 u) {
    union { float f; uint32_t i; } x; x.i = ((uint32_t)u) << 16; return x.f;
}
__device__ __forceinline__ u16 f2b(float f) {
    union { float f; uint32_t i; } x; x.f = f;
    uint32_t r = (x.i + 0x7fffu + ((x.i >> 16) & 1u)) >> 16;
    return (u16)r;
}

// ---------------- CPB: tab = relu(rel @ W1^T + b1) @ W2^T ----------------
__global__ __launch_bounds__(512)
void cpb_tab_kernel(const float* __restrict__ w1, const float* __restrict__ b1,
                    const float* __restrict__ w2, float* __restrict__ tab) {
    __shared__ float hbuf[512];
    int p = blockIdx.x, j = threadIdx.x;
    int i0 = p / 13, i1 = p % 13;
    float c0 = (i0 - 6) * (8.0f / 6.0f), c1 = (i1 - 6) * (8.0f / 6.0f);
    float r0 = copysignf(log2f(fabsf(c0) + 1.0f) * (1.0f / 3.0f), c0);
    float r1 = copysignf(log2f(fabsf(c1) + 1.0f) * (1.0f / 3.0f), c1);
    float h = r0 * w1[j * 2] + r1 * w1[j * 2 + 1] + b1[j];
    hbuf[j] = fmaxf(h, 0.0f);
    __syncthreads();
    if (j < 12) {
        float s = 0.0f;
        for (int t = 0; t < 512; t++) s += w2[j * 512 + t] * hbuf[t];
        tab[p * 12 + j] = s;
    }
}

__global__ __launch_bounds__(256)
void cpb_gather_kernel(const float* __restrict__ tab, float* __restrict__ rpb) {
    int idx = blockIdx.x * 256 + threadIdx.x;
    if (idx >= 12 * 2401) return;
    int h = idx / 2401, r = idx % 2401, i = r / 49, j = r % 49;
    int d = (i / 7 - j / 7 + 6) * 13 + (i % 7 - j % 7 + 6);
    float v = tab[d * 12 + h];
    rpb[idx] = 16.0f / (1.0f + expf(-v));
}

// ---------------- combined bias: out[(w*12+h)*2401 + ij] = rpb[h] + mask[w] ----------------
__global__ __launch_bounds__(256)
void bias_combine_kernel(const float* __restrict__ rpb, const float* __restrict__ mask,
                         float* __restrict__ outb) {
    int idx = blockIdx.x * 256 + threadIdx.x;
    if (idx >= 768 * 2401) return;
    int wh = idx / 2401, ij = idx - wh * 2401;
    int w = wh / 12, h = wh - w * 12;
    outb[idx] = rpb[h * 2401 + ij] + mask[w * 2401 + ij];
}

// ---------------- LN stats: one wave per token (raster order, fp32 in) ----------------
__global__ __launch_bounds__(256)
void ln_stats_kernel(const float* __restrict__ in, float2* __restrict__ st) {
    int wave = threadIdx.x >> 6, lane = threadIdx.x & 63;
    int tok = blockIdx.x * 4 + wave;
    size_t src = (size_t)tok * 384;
    float s = 0.0f, s2 = 0.0f;
#pragma unroll
    for (int i = 0; i < 6; i++) {
        float t = in[src + i * 64 + lane];
        s += t; s2 += t * t;
    }
#pragma unroll
    for (int m = 32; m >= 1; m >>= 1) { s += __shfl_xor(s, m, 64); s2 += __shfl_xor(s2, m, 64); }
    if (lane == 0) {
        float mu = s * (1.0f / 384.0f);
        float var = s2 * (1.0f / 384.0f) - mu * mu;
        st[tok] = make_float2(mu, rsqrtf(var + 1e-5f));
    }
}

// ---------------- MFMA GEMM: fp32/bf16 A sources, fp32 W, fused epilogues ----------------
enum { SRC_WINLN = 0, SRC_HEADMAJ = 1, SRC_RASTLN = 2, SRC_PLAIN = 3 };
enum { EPI_QKV = 0, EPI_PROJ = 1, EPI_MLP1 = 2, EPI_MLP2 = 3 };
#define LDP 40

template <int SRC, int EPI>
__global__ __launch_bounds__(256)
void gemm_mfma(const void* __restrict__ Av, const float* __restrict__ W,
               const float* __restrict__ bias, int K,
               const float2* __restrict__ stats,
               const float* __restrict__ lng, const float* __restrict__ lnb,
               u16* __restrict__ o0, u16* __restrict__ o1, u16* __restrict__ o2,
               const float* __restrict__ xres, float* __restrict__ dout) {
    const float* Af = (const float*)Av;
    const u16*   Ab = (const u16*)Av;
    const int tid = threadIdx.x;
    const int wave = tid >> 6, lane = tid & 63, quad = lane >> 4, l16 = lane & 15;
    const int wm = (wave >> 1) * 64, wn = (wave & 1) * 64;
    const int m0 = blockIdx.y * 128, n0 = blockIdx.x * 128;
    __shared__ alignas(16) u16 lA[128 * LDP];
    __shared__ alignas(16) u16 lB[128 * LDP];
    f32x4 acc[4][4] = {};

    // fixed per-thread staging rows: precompute source base + LN stats
    size_t abase[2];
    float amu[2] = {0.f, 0.f}, arst[2] = {0.f, 0.f};
#pragma unroll
    for (int s = 0; s < 2; s++) {
        int row = (tid + s * 256) >> 2;
        int grow = m0 + row;
        if (SRC == SRC_WINLN) {
            int widx = grow / 49, n = grow % 49;
            int bb = widx >> 6, wi = widx & 63;
            int hs = (wi >> 3) * 7 + n / 7, wsr = (wi & 7) * 7 + n % 7;
            int h = hs + 3; if (h >= 56) h -= 56;
            int w = wsr + 3; if (w >= 56) w -= 56;
            int tok = bb * 3136 + h * 56 + w;
            abase[s] = (size_t)tok * 384;
            float2 st = stats[tok]; amu[s] = st.x; arst[s] = st.y;
        } else if (SRC == SRC_HEADMAJ) {
            int widx = grow / 49, n = grow % 49;
            abase[s] = (size_t)widx * 18816 + (size_t)n * 32;   // 12*1568
        } else if (SRC == SRC_RASTLN) {
            abase[s] = (size_t)grow * 384;
            float2 st = stats[grow]; amu[s] = st.x; arst[s] = st.y;
        } else {
            abase[s] = (size_t)grow * (size_t)K;
        }
    }

    for (int kk = 0; kk < K; kk += 32) {
        __syncthreads();
#pragma unroll
        for (int s = 0; s < 2; s++) {
            int c = tid + s * 256;
            int row = c >> 2, seg = c & 3;
            // ---- A ----
            u16 oa[8];
            if (SRC == SRC_HEADMAJ || SRC == SRC_PLAIN) {
                size_t off = (SRC == SRC_HEADMAJ)
                                 ? (size_t)(kk >> 5) * 1568 + seg * 8
                                 : (size_t)kk + seg * 8;
                *(int4*)oa = *(const int4*)&Ab[abase[s] + off];
            } else {
                const float* sp = Af + abase[s] + kk + seg * 8;
                float4 r0 = *(const float4*)sp, r1 = *(const float4*)(sp + 4);
                float vv[8] = {r0.x, r0.y, r0.z, r0.w, r1.x, r1.y, r1.z, r1.w};
                int cb = kk + seg * 8;
#pragma unroll
                for (int e = 0; e < 8; e++)
                    oa[e] = f2b((vv[e] - amu[s]) * arst[s] * lng[cb + e] + lnb[cb + e]);
            }
            *(int4*)&lA[row * LDP + seg * 8] = *(int4*)oa;
            // ---- B (fp32 weights -> bf16) ----
            const float* wp = W + (size_t)(n0 + row) * K + kk + seg * 8;
            float4 w0 = *(const float4*)wp, w1 = *(const float4*)(wp + 4);
            float wv[8] = {w0.x, w0.y, w0.z, w0.w, w1.x, w1.y, w1.z, w1.w};
            u16 ob[8];
#pragma unroll
            for (int e = 0; e < 8; e++) ob[e] = f2b(wv[e]);
            *(int4*)&lB[row * LDP + seg * 8] = *(int4*)ob;
        }
        __syncthreads();
        bf16x8 af[4], bfr[4];
#pragma unroll
        for (int t = 0; t < 4; t++)
            af[t] = *(const bf16x8*)&lA[(wm + t * 16 + l16) * LDP + quad * 8];
#pragma unroll
        for (int t = 0; t < 4; t++)
            bfr[t] = *(const bf16x8*)&lB[(wn + t * 16 + l16) * LDP + quad * 8];
#pragma unroll
        for (int i = 0; i < 4; i++)
#pragma unroll
            for (int j = 0; j < 4; j++)
                acc[i][j] = __builtin_amdgcn_mfma_f32_16x16x32_bf16(af[i], bfr[j], acc[i][j], 0, 0, 0);
    }

#pragma unroll
    for (int i = 0; i < 4; i++) {
#pragma unroll
        for (int r = 0; r < 4; r++) {
            int row = m0 + wm + i * 16 + quad * 4 + r;  // token index
            int widx = 0, n = 0;
            size_t pbase = 0;
            if (EPI == EPI_QKV || EPI == EPI_PROJ) { widx = row / 49; n = row % 49; }
            if (EPI == EPI_PROJ) {
                int bb = widx >> 6, wi = widx & 63;
                int hs = (wi >> 3) * 7 + n / 7, wsr = (wi & 7) * 7 + n % 7;
                int h = hs + 3; if (h >= 56) h -= 56;
                int w = wsr + 3; if (w >= 56) w -= 56;
                pbase = (((size_t)bb * 56 + h) * 56 + w) * 384;
            }
#pragma unroll
            for (int j = 0; j < 4; j++) {
                int col = n0 + wn + j * 16 + l16;
                float v = acc[i][j][r] + bias[col];
                if (EPI == EPI_QKV) {
                    int which = col / 384, head = (col >> 5) % 12, hd = col & 31;
                    u16* dst = (which == 0) ? o0 : ((which == 1) ? o1 : o2);
                    dst[(size_t)(widx * 12 + head) * 1568 + n * 32 + hd] = f2b(v);
                } else if (EPI == EPI_PROJ) {
                    dout[pbase + col] = v + xres[pbase + col];
                } else if (EPI == EPI_MLP1) {
                    float ge = 0.5f * v * (1.0f + erff(v * 0.70710678f));
                    o0[(size_t)row * 768 + col] = f2b(ge);
                } else {  // MLP2: dout += v
                    size_t o = (size_t)row * 384 + col;
                    dout[o] = v + dout[o];
                }
            }
        }
    }
}

// ---------------- Attention: MFMA, one wave per (window, head), barrier-free ----------------
// S = Q·K^T via mfma_16x16x32_bf16 on raw bf16 q/k (norms applied as f32 post-scale,
// so S quantization is identical to the scalar version). Softmax rows fully
// wave-parallel via shfl_xor. P (bf16) bounced through wave-private LDS to build
// PV A-fragments; V transposed into LDS with zero-padded cols. No __syncthreads.
__global__ __launch_bounds__(256)
void attn_mfma_kernel(const u16* __restrict__ q, const u16* __restrict__ k,
                      const u16* __restrict__ v, const float* __restrict__ bias,
                      const float* __restrict__ lsc, u16* __restrict__ out) {
    __shared__ alignas(16) u16 sP[4][64 * 72];   // P, stride 72 bf16 (144B, 16B-aligned)
    __shared__ alignas(16) u16 sVT[4][32 * 72];  // V^T [d][j], zero-padded j>=49
    __shared__ float sQin[4][64], sKin[4][64];   // per-row inv norms
    const int tid = threadIdx.x;
    const int wave = tid >> 6, lane = tid & 63;
    const int quad = lane >> 4, l16 = lane & 15;
    const int unit = blockIdx.x * 4 + wave;      // widx*12 + head
    const int widx = unit / 12, head = unit - widx * 12;
    const size_t base = (size_t)unit * 1568;
    u16* pP  = sP[wave];
    u16* pVT = sVT[wave];
    float* qin = sQin[wave];
    float* kin = sKin[wave];

    // rows 49..63 of the inv-norm tables are never written by the norm section
    if (lane >= 49) { qin[lane] = 0.0f; kin[lane] = 0.0f; }

    // ---- stage V^T into LDS (cols 49..63 exactly zero so padded P cols are harmless) ----
    {
        const bool valid = lane < 49;
#pragma unroll
        for (int c = 0; c < 4; c++) {
            u16 r8[8] = {0, 0, 0, 0, 0, 0, 0, 0};
            if (valid) *(int4*)r8 = *(const int4*)&v[base + lane * 32 + c * 8];
#pragma unroll
            for (int e = 0; e < 8; e++) pVT[(c * 8 + e) * 72 + lane] = r8[e];
        }
    }

    // ---- load raw Q/K fragments + compute row inv-norms (f32, exact as before) ----
    const float lscale = __expf(fminf(lsc[head], 4.6051702f));
    bf16x8 qf[4], kf[4];
#pragma unroll
    for (int t = 0; t < 4; t++) {
        int row = t * 16 + l16; if (row > 48) row = 48;   // duplicate last row into padding
        int4 qa = *(const int4*)&q[base + row * 32 + quad * 8];
        int4 ka = *(const int4*)&k[base + row * 32 + quad * 8];
        u16 qu[8], ku[8];
        *(int4*)qu = qa; *(int4*)ku = ka;
        float qs2 = 0.f, ks2 = 0.f;
#pragma unroll
        for (int e = 0; e < 8; e++) {
            float a = b2f(qu[e]), b = b2f(ku[e]);
            qs2 = fmaf(a, a, qs2); ks2 = fmaf(b, b, ks2);
        }
        // full row lives in the 4 quads sharing l16
        qs2 += __shfl_xor(qs2, 16, 64); qs2 += __shfl_xor(qs2, 32, 64);
        ks2 += __shfl_xor(ks2, 16, 64); ks2 += __shfl_xor(ks2, 32, 64);
        if (quad == 0) {
            qin[row] = lscale * rsqrtf(fmaxf(qs2, 1e-24f));
            kin[row] = rsqrtf(fmaxf(ks2, 1e-24f));
        }
        qf[t] = *(bf16x8*)&qa;
        kf[t] = *(bf16x8*)&ka;
    }

    // ---- S = Q · K^T (64x64 padded), f32 accum ----
    f32x4 s[4][4] = {};
#pragma unroll
    for (int mi = 0; mi < 4; mi++)
#pragma unroll
        for (int ni = 0; ni < 4; ni++)
            s[mi][ni] = __builtin_amdgcn_mfma_f32_16x16x32_bf16(qf[mi], kf[ni], s[mi][ni], 0, 0, 0);

    // ---- softmax rows: scale by inv-norms, +combined bias, reduce across 16 lanes ----
    const float* bp = bias + (size_t)((widx & 63) * 12 + head) * 2401;
    float kj[4];
#pragma unroll
    for (int ni = 0; ni < 4; ni++) kj[ni] = kin[ni * 16 + l16];
#pragma unroll
    for (int mi = 0; mi < 4; mi++) {
#pragma unroll
        for (int r = 0; r < 4; r++) {
            const int i = mi * 16 + quad * 4 + r;       // D layout: row = quad*4+reg
            const float qi = qin[i];                    // 0 for padded rows
            const float* brow = bp + (i < 49 ? i : 48) * 49;
            float lg[4];
#pragma unroll
            for (int ni = 0; ni < 4; ni++) {
                const int j = ni * 16 + l16;            // D layout: col = l16
                lg[ni] = (j < 49) ? fmaf(s[mi][ni][r], qi * kj[ni], brow[j]) : -1e30f;
            }
            float m = fmaxf(fmaxf(lg[0], lg[1]), fmaxf(lg[2], lg[3]));
            m = fmaxf(m, __shfl_xor(m, 1, 64));
            m = fmaxf(m, __shfl_xor(m, 2, 64));
            m = fmaxf(m, __shfl_xor(m, 4, 64));
            m = fmaxf(m, __shfl_xor(m, 8, 64));
            float p0 = __expf(lg[0] - m), p1 = __expf(lg[1] - m);
            float p2 = __expf(lg[2] - m), p3 = __expf(lg[3] - m);
            float sum = p0 + p1 + p2 + p3;
            sum += __shfl_xor(sum, 1, 64);
            sum += __shfl_xor(sum, 2, 64);
            sum += __shfl_xor(sum, 4, 64);
            sum += __shfl_xor(sum, 8, 64);
            const float inv = 1.0f / sum;
            pP[i * 72 +  0 + l16] = f2b(p0 * inv);      // masked cols underflow to exact 0
            pP[i * 72 + 16 + l16] = f2b(p1 * inv);
            pP[i * 72 + 32 + l16] = f2b(p2 * inv);
            pP[i * 72 + 48 + l16] = f2b(p3 * inv);
        }
    }

    // ---- O = P · V  (A-frags from sP, B-frags from sVT; same-wave DS ops are in-order) ----
    bf16x8 vf[2][2];
#pragma unroll
    for (int kk = 0; kk < 2; kk++)
#pragma unroll
        for (int ni = 0; ni < 2; ni++)
            vf[kk][ni] = *(const bf16x8*)&pVT[(ni * 16 + l16) * 72 + kk * 32 + quad * 8];
    f32x4 o[4][2] = {};
#pragma unroll
    for (int mi = 0; mi < 4; mi++)
#pragma unroll
        for (int kk = 0; kk < 2; kk++) {
            bf16x8 pa = *(const bf16x8*)&pP[(mi * 16 + l16) * 72 + kk * 32 + quad * 8];
#pragma unroll
            for (int ni = 0; ni < 2; ni++)
                o[mi][ni] = __builtin_amdgcn_mfma_f32_16x16x32_bf16(pa, vf[kk][ni], o[mi][ni], 0, 0, 0);
        }

    // ---- write O (head-major layout, in-place over q slice) ----
#pragma unroll
    for (int mi = 0; mi < 4; mi++)
#pragma unroll
        for (int r = 0; r < 4; r++) {
            const int i = mi * 16 + quad * 4 + r;
            if (i < 49) {
                out[base + i * 32 + l16]      = f2b(o[mi][0][r]);
                out[base + i * 32 + 16 + l16] = f2b(o[mi][1][r]);
            }
        }
}

// ---------------- launch ----------------
extern "C" void kernel_launch(void* const* d_in, const int* in_sizes, int n_in,
                              void* d_out, int out_size, void* d_ws, size_t ws_size,
                              hipStream_t stream) {
    const float* x      = (const float*)d_in[0];
    const float* mask   = (const float*)d_in[1];
    const float* n1g    = (const float*)d_in[2];
    const float* n1b    = (const float*)d_in[3];
    const float* qkv_w  = (const float*)d_in[4];
    const float* qkv_b  = (const float*)d_in[5];
    const float* proj_w = (const float*)d_in[6];
    const float* proj_b = (const float*)d_in[7];
    const float* cpb_w1 = (const float*)d_in[8];
    const float* cpb_b1 = (const float*)d_in[9];
    const float* cpb_w2 = (const float*)d_in[10];
    const float* lscale = (const float*)d_in[11];
    const float* n2g    = (const float*)d_in[12];
    const float* n2b    = (const float*)d_in[13];
    const float* mlp_w1 = (const float*)d_in[14];
    const float* mlp_b1 = (const float*)d_in[15];
    const float* mlp_w2 = (const float*)d_in[16];
    const float* mlp_b2 = (const float*)d_in[17];

    char* ws = (char*)d_ws;
    const size_t SLOT = 77070336ULL;       // 100352*384*2 bytes (bf16 slot)
    float*  tab    = (float*)(ws);                 // 8112 B
    float*  rpb    = (float*)(ws + 16384);         // 115248 B
    float2* stats1 = (float2*)(ws + (1 << 20));    // 802816 B
    float2* stats2 = (float2*)(ws + (2 << 20));    // 802816 B
    u16* qb     = (u16*)(ws + (4 << 20));
    u16* kb     = (u16*)(ws + (4 << 20) + SLOT);
    u16* vb     = (u16*)d_out;              // bf16 v staged in d_out (dead before proj writes)
    u16* attn_o = qb;                       // attention writes in-place over q slices
    u16* hidden = qb;                       // q+k slots (154 MB) reused for MLP hidden
    float* dout = (float*)d_out;
    // combined rpb+mask bias lives in d_out past the V slot (7.4 MB, dead before proj)
    float* biasc = (float*)((char*)d_out + SLOT);
    // peak ws usage: 4 MB + 2*SLOT ~= 158 MB

    cpb_tab_kernel<<<169, 512, 0, stream>>>(cpb_w1, cpb_b1, cpb_w2, tab);
    cpb_gather_kernel<<<113, 256, 0, stream>>>(tab, rpb);
    bias_combine_kernel<<<7203, 256, 0, stream>>>(rpb, mask, biasc);
    ln_stats_kernel<<<25088, 256, 0, stream>>>(x, stats1);
    gemm_mfma<SRC_WINLN, EPI_QKV><<<dim3(9, 784), 256, 0, stream>>>(
        x, qkv_w, qkv_b, 384, stats1, n1g, n1b, qb, kb, vb, nullptr, nullptr);
    attn_mfma_kernel<<<6144, 256, 0, stream>>>(qb, kb, vb, biasc, lscale, attn_o);
    gemm_mfma<SRC_HEADMAJ, EPI_PROJ><<<dim3(3, 784), 256, 0, stream>>>(
        attn_o, proj_w, proj_b, 384, nullptr, nullptr, nullptr,
        nullptr, nullptr, nullptr, x, dout);
    ln_stats_kernel<<<25088, 256, 0, stream>>>(dout, stats2);
    gemm_mfma<SRC_RASTLN, EPI_MLP1><<<dim3(6, 784), 256, 0, stream>>>(
        dout, mlp_w1, mlp_b1, 384, stats2, n2g, n2b,
        hidden, nullptr, nullptr, nullptr, nullptr);
    gemm_mfma<SRC_PLAIN, EPI_MLP2><<<dim3(3, 784), 256, 0, stream>>>(
        hidden, mlp_w2, mlp_b2, 768, nullptr, nullptr, nullptr,
        nullptr, nullptr, nullptr, nullptr, dout);
}

// Round 2
// 1171.505 us; speedup vs baseline: 1.4695x; 1.1219x over previous
//
#include <hip/hip_runtime.h>
#include <stdint.h>

typedef unsigned short u16;
typedef __bf16 bf16x8 __attribute__((ext_vector_type(8)));
typedef float f32x4 __attribute__((ext_vector_type(4)));

__device__ __forceinline__ float b2f(u16 u) {
    union { float f; uint32_t i; } x; x.i = ((uint32_t)u) << 16; return x.f;
}
__device__ __forceinline__ u16 f2b(float f) {
    union { float f; uint32_t i; } x; x.f = f;
    uint32_t r = (x.i + 0x7fffu + ((x.i >> 16) & 1u)) >> 16;
    return (u16)r;
}

// ---------------- CPB: tab = relu(rel @ W1^T + b1) @ W2^T ----------------
__global__ __launch_bounds__(512)
void cpb_tab_kernel(const float* __restrict__ w1, const float* __restrict__ b1,
                    const float* __restrict__ w2, float* __restrict__ tab) {
    __shared__ float hbuf[512];
    int p = blockIdx.x, j = threadIdx.x;
    int i0 = p / 13, i1 = p % 13;
    float c0 = (i0 - 6) * (8.0f / 6.0f), c1 = (i1 - 6) * (8.0f / 6.0f);
    float r0 = copysignf(log2f(fabsf(c0) + 1.0f) * (1.0f / 3.0f), c0);
    float r1 = copysignf(log2f(fabsf(c1) + 1.0f) * (1.0f / 3.0f), c1);
    float h = r0 * w1[j * 2] + r1 * w1[j * 2 + 1] + b1[j];
    hbuf[j] = fmaxf(h, 0.0f);
    __syncthreads();
    if (j < 12) {
        float s = 0.0f;
        for (int t = 0; t < 512; t++) s += w2[j * 512 + t] * hbuf[t];
        tab[p * 12 + j] = s;
    }
}

__global__ __launch_bounds__(256)
void cpb_gather_kernel(const float* __restrict__ tab, float* __restrict__ rpb) {
    int idx = blockIdx.x * 256 + threadIdx.x;
    if (idx >= 12 * 2401) return;
    int h = idx / 2401, r = idx % 2401, i = r / 49, j = r % 49;
    int d = (i / 7 - j / 7 + 6) * 13 + (i % 7 - j % 7 + 6);
    float v = tab[d * 12 + h];
    rpb[idx] = 16.0f / (1.0f + expf(-v));
}

// ---------------- weights fp32 -> bf16, all four matrices packed ----------------
__global__ __launch_bounds__(256)
void wconv_kernel(const float* __restrict__ s0, const float* __restrict__ s1,
                  const float* __restrict__ s2, const float* __restrict__ s3,
                  u16* __restrict__ dst) {
    int i = (blockIdx.x * 256 + threadIdx.x) * 4;
    if (i >= 1179648) return;
    const float* src; int off;
    if (i < 442368)      { src = s0; off = i; }
    else if (i < 589824) { src = s1; off = i - 442368; }
    else if (i < 884736) { src = s2; off = i - 589824; }
    else                 { src = s3; off = i - 884736; }
    float4 v = *(const float4*)(src + off);
    u16 o[4] = {f2b(v.x), f2b(v.y), f2b(v.z), f2b(v.w)};
    *(uint2*)(dst + i) = *(const uint2*)o;
}

// ---------------- fused LN: stats + apply + bf16 write (PERM: shifted-window rows) ----------------
template <int PERM>
__global__ __launch_bounds__(256)
void ln_fused_kernel(const float* __restrict__ in, const float* __restrict__ g,
                     const float* __restrict__ b, u16* __restrict__ outb) {
    int wave = threadIdx.x >> 6, lane = threadIdx.x & 63;
    int tok = blockIdx.x * 4 + wave;
    size_t src = (size_t)tok * 384;
    float2 v[3];
    float s = 0.0f, s2 = 0.0f;
#pragma unroll
    for (int i = 0; i < 3; i++) {
        v[i] = *(const float2*)&in[src + i * 128 + lane * 2];
        s += v[i].x + v[i].y;
        s2 += v[i].x * v[i].x + v[i].y * v[i].y;
    }
#pragma unroll
    for (int m = 32; m >= 1; m >>= 1) { s += __shfl_xor(s, m, 64); s2 += __shfl_xor(s2, m, 64); }
    float mu = s * (1.0f / 384.0f);
    float rstd = rsqrtf(s2 * (1.0f / 384.0f) - mu * mu + 1e-5f);
    int drow = tok;
    if (PERM) {
        int bb = tok / 3136, rr = tok % 3136;
        int h = rr / 56, w = rr % 56;
        int hs = h - 3; if (hs < 0) hs += 56;
        int wsr = w - 3; if (wsr < 0) wsr += 56;
        int wi = (hs / 7) * 8 + (wsr / 7);
        int n = (hs % 7) * 7 + (wsr % 7);
        drow = (bb * 64 + wi) * 49 + n;
    }
    size_t dst = (size_t)drow * 384;
#pragma unroll
    for (int i = 0; i < 3; i++) {
        int c = i * 128 + lane * 2;
        float2 gg = *(const float2*)&g[c];
        float2 bv = *(const float2*)&b[c];
        u16 o[2] = { f2b((v[i].x - mu) * rstd * gg.x + bv.x),
                     f2b((v[i].y - mu) * rstd * gg.y + bv.y) };
        *(uint32_t*)&outb[dst + c] = *(const uint32_t*)o;
    }
}

// ---------------- MFMA GEMM: bf16 A, bf16 W, fused epilogues ----------------
enum { SRC_PLAIN = 0, SRC_HEADMAJ = 1 };
enum { EPI_QKV = 0, EPI_PROJ = 1, EPI_MLP1 = 2, EPI_MLP2 = 3 };
#define LDP 40

template <int SRC, int EPI>
__global__ __launch_bounds__(256)
void gemm_mfma(const u16* __restrict__ A, const u16* __restrict__ Wb,
               const float* __restrict__ bias, int K,
               u16* __restrict__ o0, u16* __restrict__ o1, u16* __restrict__ o2,
               const float* __restrict__ xres, float* __restrict__ dout) {
    const int tid = threadIdx.x;
    const int wave = tid >> 6, lane = tid & 63, quad = lane >> 4, l16 = lane & 15;
    const int wm = (wave >> 1) * 64, wn = (wave & 1) * 64;
    const int m0 = blockIdx.y * 128, n0 = blockIdx.x * 128;
    __shared__ alignas(16) u16 lA[128 * LDP];
    __shared__ alignas(16) u16 lB[128 * LDP];
    f32x4 acc[4][4] = {};

    // fixed per-thread staging rows: precompute A and W source bases
    size_t abase[2], wbase[2];
#pragma unroll
    for (int s = 0; s < 2; s++) {
        int row = (tid + s * 256) >> 2;
        int grow = m0 + row;
        if (SRC == SRC_HEADMAJ) {
            int widx = grow / 49, n = grow % 49;
            abase[s] = (size_t)widx * 18816 + (size_t)n * 32;   // 12*1568
        } else {
            abase[s] = (size_t)grow * (size_t)K;
        }
        wbase[s] = (size_t)(n0 + row) * (size_t)K;
    }

    for (int kk = 0; kk < K; kk += 32) {
        __syncthreads();
#pragma unroll
        for (int s = 0; s < 2; s++) {
            int c = tid + s * 256;
            int row = c >> 2, seg = c & 3;
            size_t aoff = (SRC == SRC_HEADMAJ)
                              ? (size_t)(kk >> 5) * 1568 + seg * 8
                              : (size_t)kk + seg * 8;
            *(int4*)&lA[row * LDP + seg * 8] = *(const int4*)&A[abase[s] + aoff];
            *(int4*)&lB[row * LDP + seg * 8] = *(const int4*)&Wb[wbase[s] + kk + seg * 8];
        }
        __syncthreads();
        bf16x8 af[4], bfr[4];
#pragma unroll
        for (int t = 0; t < 4; t++)
            af[t] = *(const bf16x8*)&lA[(wm + t * 16 + l16) * LDP + quad * 8];
#pragma unroll
        for (int t = 0; t < 4; t++)
            bfr[t] = *(const bf16x8*)&lB[(wn + t * 16 + l16) * LDP + quad * 8];
#pragma unroll
        for (int i = 0; i < 4; i++)
#pragma unroll
            for (int j = 0; j < 4; j++)
                acc[i][j] = __builtin_amdgcn_mfma_f32_16x16x32_bf16(af[i], bfr[j], acc[i][j], 0, 0, 0);
    }

#pragma unroll
    for (int i = 0; i < 4; i++) {
#pragma unroll
        for (int r = 0; r < 4; r++) {
            int row = m0 + wm + i * 16 + quad * 4 + r;  // token index (window order / local)
            int widx = 0, n = 0;
            size_t pbase = 0;
            if (EPI == EPI_QKV || EPI == EPI_PROJ) { widx = row / 49; n = row % 49; }
            if (EPI == EPI_PROJ) {
                int bb = widx >> 6, wi = widx & 63;
                int hs = (wi >> 3) * 7 + n / 7, wsr = (wi & 7) * 7 + n % 7;
                int h = hs + 3; if (h >= 56) h -= 56;
                int w = wsr + 3; if (w >= 56) w -= 56;
                pbase = (((size_t)bb * 56 + h) * 56 + w) * 384;
            }
#pragma unroll
            for (int j = 0; j < 4; j++) {
                int col = n0 + wn + j * 16 + l16;
                float v = acc[i][j][r] + bias[col];
                if (EPI == EPI_QKV) {
                    int which = col / 384, head = (col >> 5) % 12, hd = col & 31;
                    u16* dst = (which == 0) ? o0 : ((which == 1) ? o1 : o2);
                    dst[(size_t)(widx * 12 + head) * 1568 + n * 32 + hd] = f2b(v);
                } else if (EPI == EPI_PROJ) {
                    dout[pbase + col] = v + xres[pbase + col];
                } else if (EPI == EPI_MLP1) {
                    float ge = 0.5f * v * (1.0f + erff(v * 0.70710678f));
                    o0[(size_t)row * 768 + col] = f2b(ge);
                } else {  // MLP2: dout += v
                    size_t o = (size_t)row * 384 + col;
                    dout[o] = v + dout[o];
                }
            }
        }
    }
}

// ---------------- Attention: MFMA, one wave per (window, head), barrier-free ----------------
__global__ __launch_bounds__(256)
void attn_mfma_kernel(const u16* __restrict__ q, const u16* __restrict__ k,
                      const u16* __restrict__ v, const float* __restrict__ rpb,
                      const float* __restrict__ mask, const float* __restrict__ lsc,
                      u16* __restrict__ out) {
    __shared__ alignas(16) u16 sP[4][64 * 72];   // P, stride 72 bf16 (144B, 16B-aligned)
    __shared__ alignas(16) u16 sVT[4][32 * 72];  // V^T [d][j], zero-padded j>=49
    __shared__ float sQin[4][64], sKin[4][64];   // per-row inv norms
    const int tid = threadIdx.x;
    const int wave = tid >> 6, lane = tid & 63;
    const int quad = lane >> 4, l16 = lane & 15;
    const int unit = blockIdx.x * 4 + wave;      // widx*12 + head
    const int widx = unit / 12, head = unit - widx * 12;
    const size_t base = (size_t)unit * 1568;
    u16* pP  = sP[wave];
    u16* pVT = sVT[wave];
    float* qin = sQin[wave];
    float* kin = sKin[wave];

    if (lane >= 49) { qin[lane] = 0.0f; kin[lane] = 0.0f; }

    // ---- stage V^T into LDS (cols 49..63 exactly zero) ----
    {
        const bool valid = lane < 49;
#pragma unroll
        for (int c = 0; c < 4; c++) {
            u16 r8[8] = {0, 0, 0, 0, 0, 0, 0, 0};
            if (valid) *(int4*)r8 = *(const int4*)&v[base + lane * 32 + c * 8];
#pragma unroll
            for (int e = 0; e < 8; e++) pVT[(c * 8 + e) * 72 + lane] = r8[e];
        }
    }

    // ---- load raw Q/K fragments + compute row inv-norms ----
    const float lscale = __expf(fminf(lsc[head], 4.6051702f));
    bf16x8 qf[4], kf[4];
#pragma unroll
    for (int t = 0; t < 4; t++) {
        int row = t * 16 + l16; if (row > 48) row = 48;   // duplicate last row into padding
        int4 qa = *(const int4*)&q[base + row * 32 + quad * 8];
        int4 ka = *(const int4*)&k[base + row * 32 + quad * 8];
        u16 qu[8], ku[8];
        *(int4*)qu = qa; *(int4*)ku = ka;
        float qs2 = 0.f, ks2 = 0.f;
#pragma unroll
        for (int e = 0; e < 8; e++) {
            float a = b2f(qu[e]), b = b2f(ku[e]);
            qs2 = fmaf(a, a, qs2); ks2 = fmaf(b, b, ks2);
        }
        qs2 += __shfl_xor(qs2, 16, 64); qs2 += __shfl_xor(qs2, 32, 64);
        ks2 += __shfl_xor(ks2, 16, 64); ks2 += __shfl_xor(ks2, 32, 64);
        if (quad == 0) {
            qin[row] = lscale * rsqrtf(fmaxf(qs2, 1e-24f));
            kin[row] = rsqrtf(fmaxf(ks2, 1e-24f));
        }
        qf[t] = *(bf16x8*)&qa;
        kf[t] = *(bf16x8*)&ka;
    }

    // ---- S = Q · K^T (64x64 padded), f32 accum ----
    f32x4 s[4][4] = {};
#pragma unroll
    for (int mi = 0; mi < 4; mi++)
#pragma unroll
        for (int ni = 0; ni < 4; ni++)
            s[mi][ni] = __builtin_amdgcn_mfma_f32_16x16x32_bf16(qf[mi], kf[ni], s[mi][ni], 0, 0, 0);

    // ---- softmax rows ----
    const float* rp = rpb + (size_t)head * 2401;
    const float* mk = mask + (size_t)(widx & 63) * 2401;
    float kj[4];
#pragma unroll
    for (int ni = 0; ni < 4; ni++) kj[ni] = kin[ni * 16 + l16];
#pragma unroll
    for (int mi = 0; mi < 4; mi++) {
#pragma unroll
        for (int r = 0; r < 4; r++) {
            const int i = mi * 16 + quad * 4 + r;       // D layout: row = quad*4+reg
            const float qi = qin[i];                    // 0 for padded rows
            const int ic = (i < 49 ? i : 48) * 49;
            const float* brow = rp + ic;
            const float* mrow = mk + ic;
            float lg[4];
#pragma unroll
            for (int ni = 0; ni < 4; ni++) {
                const int j = ni * 16 + l16;            // D layout: col = l16
                lg[ni] = (j < 49) ? fmaf(s[mi][ni][r], qi * kj[ni], brow[j] + mrow[j]) : -1e30f;
            }
            float m = fmaxf(fmaxf(lg[0], lg[1]), fmaxf(lg[2], lg[3]));
            m = fmaxf(m, __shfl_xor(m, 1, 64));
            m = fmaxf(m, __shfl_xor(m, 2, 64));
            m = fmaxf(m, __shfl_xor(m, 4, 64));
            m = fmaxf(m, __shfl_xor(m, 8, 64));
            float p0 = __expf(lg[0] - m), p1 = __expf(lg[1] - m);
            float p2 = __expf(lg[2] - m), p3 = __expf(lg[3] - m);
            float sum = p0 + p1 + p2 + p3;
            sum += __shfl_xor(sum, 1, 64);
            sum += __shfl_xor(sum, 2, 64);
            sum += __shfl_xor(sum, 4, 64);
            sum += __shfl_xor(sum, 8, 64);
            const float inv = 1.0f / sum;
            pP[i * 72 +  0 + l16] = f2b(p0 * inv);
            pP[i * 72 + 16 + l16] = f2b(p1 * inv);
            pP[i * 72 + 32 + l16] = f2b(p2 * inv);
            pP[i * 72 + 48 + l16] = f2b(p3 * inv);
        }
    }

    // ---- O = P · V ----
    bf16x8 vf[2][2];
#pragma unroll
    for (int kk = 0; kk < 2; kk++)
#pragma unroll
        for (int ni = 0; ni < 2; ni++)
            vf[kk][ni] = *(const bf16x8*)&pVT[(ni * 16 + l16) * 72 + kk * 32 + quad * 8];
    f32x4 o[4][2] = {};
#pragma unroll
    for (int mi = 0; mi < 4; mi++)
#pragma unroll
        for (int kk = 0; kk < 2; kk++) {
            bf16x8 pa = *(const bf16x8*)&pP[(mi * 16 + l16) * 72 + kk * 32 + quad * 8];
#pragma unroll
            for (int ni = 0; ni < 2; ni++)
                o[mi][ni] = __builtin_amdgcn_mfma_f32_16x16x32_bf16(pa, vf[kk][ni], o[mi][ni], 0, 0, 0);
        }

    // ---- write O (head-major layout, in-place over q slice) ----
#pragma unroll
    for (int mi = 0; mi < 4; mi++)
#pragma unroll
        for (int r = 0; r < 4; r++) {
            const int i = mi * 16 + quad * 4 + r;
            if (i < 49) {
                out[base + i * 32 + l16]      = f2b(o[mi][0][r]);
                out[base + i * 32 + 16 + l16] = f2b(o[mi][1][r]);
            }
        }
}

// ---------------- launch ----------------
extern "C" void kernel_launch(void* const* d_in, const int* in_sizes, int n_in,
                              void* d_out, int out_size, void* d_ws, size_t ws_size,
                              hipStream_t stream) {
    const float* x      = (const float*)d_in[0];
    const float* mask   = (const float*)d_in[1];
    const float* n1g    = (const float*)d_in[2];
    const float* n1b    = (const float*)d_in[3];
    const float* qkv_w  = (const float*)d_in[4];
    const float* qkv_b  = (const float*)d_in[5];
    const float* proj_w = (const float*)d_in[6];
    const float* proj_b = (const float*)d_in[7];
    const float* cpb_w1 = (const float*)d_in[8];
    const float* cpb_b1 = (const float*)d_in[9];
    const float* cpb_w2 = (const float*)d_in[10];
    const float* lscale = (const float*)d_in[11];
    const float* n2g    = (const float*)d_in[12];
    const float* n2b    = (const float*)d_in[13];
    const float* mlp_w1 = (const float*)d_in[14];
    const float* mlp_b1 = (const float*)d_in[15];
    const float* mlp_w2 = (const float*)d_in[16];
    const float* mlp_b2 = (const float*)d_in[17];

    char* ws = (char*)d_ws;
    const size_t SLOT = 77070336ULL;       // 100352*384*2 bytes (bf16 slot)
    float* tab = (float*)(ws);                     // 8112 B
    float* rpb = (float*)(ws + 16384);             // 115248 B
    u16*  Wb   = (u16*)(ws + (1 << 20));           // 2.36 MB bf16 weights (4 matrices)
    u16*  qkv_wb  = Wb;                            // 442368 el
    u16*  proj_wb = Wb + 442368;                   // 147456 el
    u16*  mlp1_wb = Wb + 589824;                   // 294912 el
    u16*  mlp2_wb = Wb + 884736;                   // 294912 el
    u16* qb = (u16*)(ws + (4 << 20));
    u16* kb = (u16*)(ws + (4 << 20) + SLOT);
    u16* vb = (u16*)d_out;                         // bf16 V staged in d_out[0:SLOT]
    u16* xb = (u16*)((char*)d_out + SLOT);         // LN1 bf16 (window rows) in d_out[SLOT:2*SLOT]
    u16* attn_o = qb;                              // attention writes in-place over q slices
    u16* xb2    = kb;                              // LN2 bf16 (raster rows), kb dead post-attn
    u16* hidden = qb;                              // per-half MLP hidden (50176*768*2 = SLOT)
    float* dout = (float*)d_out;
    // peak ws usage: 4 MB + 2*SLOT ~= 158 MB (unchanged)

    wconv_kernel<<<1152, 256, 0, stream>>>(qkv_w, proj_w, mlp_w1, mlp_w2, Wb);
    cpb_tab_kernel<<<169, 512, 0, stream>>>(cpb_w1, cpb_b1, cpb_w2, tab);
    cpb_gather_kernel<<<113, 256, 0, stream>>>(tab, rpb);
    ln_fused_kernel<1><<<25088, 256, 0, stream>>>(x, n1g, n1b, xb);
    gemm_mfma<SRC_PLAIN, EPI_QKV><<<dim3(9, 784), 256, 0, stream>>>(
        xb, qkv_wb, qkv_b, 384, qb, kb, vb, nullptr, nullptr);
    attn_mfma_kernel<<<6144, 256, 0, stream>>>(qb, kb, vb, rpb, mask, lscale, attn_o);
    gemm_mfma<SRC_HEADMAJ, EPI_PROJ><<<dim3(3, 784), 256, 0, stream>>>(
        attn_o, proj_wb, proj_b, 384, nullptr, nullptr, nullptr, x, dout);
    ln_fused_kernel<0><<<25088, 256, 0, stream>>>(dout, n2g, n2b, xb2);
    for (int h = 0; h < 2; h++) {
        gemm_mfma<SRC_PLAIN, EPI_MLP1><<<dim3(6, 392), 256, 0, stream>>>(
            xb2 + (size_t)h * 50176 * 384, mlp1_wb, mlp_b1, 384,
            hidden, nullptr, nullptr, nullptr, nullptr);
        gemm_mfma<SRC_PLAIN, EPI_MLP2><<<dim3(3, 392), 256, 0, stream>>>(
            hidden, mlp2_wb, mlp_b2, 768, nullptr, nullptr, nullptr,
            nullptr, dout + (size_t)h * 50176 * 384);
    }
}

// Round 3
// 1118.200 us; speedup vs baseline: 1.5396x; 1.0477x over previous
//
#include <hip/hip_runtime.h>
#include <stdint.h>

typedef unsigned short u16;
typedef __bf16 bf16x8 __attribute__((ext_vector_type(8)));
typedef float f32x4 __attribute__((ext_vector_type(4)));

__device__ __forceinline__ float b2f(u16 u) {
    union { float f; uint32_t i; } x; x.i = ((uint32_t)u) << 16; return x.f;
}
__device__ __forceinline__ u16 f2b(float f) {
    union { float f; uint32_t i; } x; x.f = f;
    uint32_t r = (x.i + 0x7fffu + ((x.i >> 16) & 1u)) >> 16;
    return (u16)r;
}
__device__ __forceinline__ void gll16(const void* g, void* l) {
    __builtin_amdgcn_global_load_lds((const __attribute__((address_space(1))) void*)g,
                                     (__attribute__((address_space(3))) void*)l, 16, 0, 0);
}

// ---------------- CPB: tab = relu(rel @ W1^T + b1) @ W2^T ----------------
__global__ __launch_bounds__(512)
void cpb_tab_kernel(const float* __restrict__ w1, const float* __restrict__ b1,
                    const float* __restrict__ w2, float* __restrict__ tab) {
    __shared__ float hbuf[512];
    int p = blockIdx.x, j = threadIdx.x;
    int i0 = p / 13, i1 = p % 13;
    float c0 = (i0 - 6) * (8.0f / 6.0f), c1 = (i1 - 6) * (8.0f / 6.0f);
    float r0 = copysignf(log2f(fabsf(c0) + 1.0f) * (1.0f / 3.0f), c0);
    float r1 = copysignf(log2f(fabsf(c1) + 1.0f) * (1.0f / 3.0f), c1);
    float h = r0 * w1[j * 2] + r1 * w1[j * 2 + 1] + b1[j];
    hbuf[j] = fmaxf(h, 0.0f);
    __syncthreads();
    if (j < 12) {
        float s = 0.0f;
        for (int t = 0; t < 512; t++) s += w2[j * 512 + t] * hbuf[t];
        tab[p * 12 + j] = s;
    }
}

__global__ __launch_bounds__(256)
void cpb_gather_kernel(const float* __restrict__ tab, float* __restrict__ rpb) {
    int idx = blockIdx.x * 256 + threadIdx.x;
    if (idx >= 12 * 2401) return;
    int h = idx / 2401, r = idx % 2401, i = r / 49, j = r % 49;
    int d = (i / 7 - j / 7 + 6) * 13 + (i % 7 - j % 7 + 6);
    float v = tab[d * 12 + h];
    rpb[idx] = 16.0f / (1.0f + expf(-v));
}

// ---------------- weights fp32 -> bf16, all four matrices packed ----------------
__global__ __launch_bounds__(256)
void wconv_kernel(const float* __restrict__ s0, const float* __restrict__ s1,
                  const float* __restrict__ s2, const float* __restrict__ s3,
                  u16* __restrict__ dst) {
    int i = (blockIdx.x * 256 + threadIdx.x) * 4;
    if (i >= 1179648) return;
    const float* src; int off;
    if (i < 442368)      { src = s0; off = i; }
    else if (i < 589824) { src = s1; off = i - 442368; }
    else if (i < 884736) { src = s2; off = i - 589824; }
    else                 { src = s3; off = i - 884736; }
    float4 v = *(const float4*)(src + off);
    u16 o[4] = {f2b(v.x), f2b(v.y), f2b(v.z), f2b(v.w)};
    *(uint2*)(dst + i) = *(const uint2*)o;
}

// ---------------- fused LN: stats + apply + bf16 write (PERM: shifted-window rows) ----------------
template <int PERM>
__global__ __launch_bounds__(256)
void ln_fused_kernel(const float* __restrict__ in, const float* __restrict__ g,
                     const float* __restrict__ b, u16* __restrict__ outb) {
    int wave = threadIdx.x >> 6, lane = threadIdx.x & 63;
    int tok = blockIdx.x * 4 + wave;
    size_t src = (size_t)tok * 384;
    float2 v[3];
    float s = 0.0f, s2 = 0.0f;
#pragma unroll
    for (int i = 0; i < 3; i++) {
        v[i] = *(const float2*)&in[src + i * 128 + lane * 2];
        s += v[i].x + v[i].y;
        s2 += v[i].x * v[i].x + v[i].y * v[i].y;
    }
#pragma unroll
    for (int m = 32; m >= 1; m >>= 1) { s += __shfl_xor(s, m, 64); s2 += __shfl_xor(s2, m, 64); }
    float mu = s * (1.0f / 384.0f);
    float rstd = rsqrtf(s2 * (1.0f / 384.0f) - mu * mu + 1e-5f);
    int drow = tok;
    if (PERM) {
        int bb = tok / 3136, rr = tok % 3136;
        int h = rr / 56, w = rr % 56;
        int hs = h - 3; if (hs < 0) hs += 56;
        int wsr = w - 3; if (wsr < 0) wsr += 56;
        int wi = (hs / 7) * 8 + (wsr / 7);
        int n = (hs % 7) * 7 + (wsr % 7);
        drow = (bb * 64 + wi) * 49 + n;
    }
    size_t dst = (size_t)drow * 384;
#pragma unroll
    for (int i = 0; i < 3; i++) {
        int c = i * 128 + lane * 2;
        float2 gg = *(const float2*)&g[c];
        float2 bv = *(const float2*)&b[c];
        u16 o[2] = { f2b((v[i].x - mu) * rstd * gg.x + bv.x),
                     f2b((v[i].y - mu) * rstd * gg.y + bv.y) };
        *(uint32_t*)&outb[dst + c] = *(const uint32_t*)o;
    }
}

// ---------------- MFMA GEMM: bf16 A/W, global_load_lds staging, XOR-swizzled LDS ----------------
// LDS tile [128][32] bf16 linear (64B rows). Both-sides swizzle (rule 21):
// linear LDS dest, global source chunk = c ^ ((row>>1)&3), same XOR on frag reads.
// XCD-chunked block swizzle: nwg % 8 == 0 for all instances.
enum { SRC_PLAIN = 0, SRC_HEADMAJ = 1 };
enum { EPI_QKV = 0, EPI_PROJ = 1, EPI_MLP1 = 2, EPI_MLP2 = 3 };

template <int SRC, int EPI, int GX>
__global__ __launch_bounds__(256)
void gemm_mfma(const u16* __restrict__ A, const u16* __restrict__ Wb,
               const float* __restrict__ bias, int K,
               u16* __restrict__ o0, u16* __restrict__ o1, u16* __restrict__ o2,
               const float* __restrict__ xres, float* __restrict__ dout) {
    const int tid = threadIdx.x;
    const int wave = tid >> 6, lane = tid & 63, quad = lane >> 4, l16 = lane & 15;
    const int wm = (wave >> 1) * 64, wn = (wave & 1) * 64;
    // XCD-chunked bijective remap (consecutive nb on one XCD)
    const int bid = blockIdx.x;
    const int nb = (bid & 7) * ((int)gridDim.x >> 3) + (bid >> 3);
    const int m0 = (nb / GX) * 128, n0 = (nb % GX) * 128;
    __shared__ alignas(16) u16 lA[128 * 32];
    __shared__ alignas(16) u16 lB[128 * 32];
    f32x4 acc[4][4] = {};

    // staging: per thread, 2 issues per matrix; issue s covers LDS rows (wave*2+s)*16 + (lane>>2)
    const int c4 = lane & 3, rsub = lane >> 2;
    size_t agb[2], wgb[2];
#pragma unroll
    for (int s = 0; s < 2; s++) {
        int row = (wave * 2 + s) * 16 + rsub;           // 0..127
        int swz = (c4 ^ ((row >> 1) & 3)) * 16;          // byte chunk, inverse-swizzled
        int grow = m0 + row;
        if (SRC == SRC_HEADMAJ) {
            int widx = grow / 49, n = grow % 49;
            agb[s] = ((size_t)widx * 18816 + (size_t)n * 32) * 2 + swz;
        } else {
            agb[s] = (size_t)grow * (size_t)K * 2 + swz;
        }
        wgb[s] = (size_t)(n0 + row) * (size_t)K * 2 + swz;
    }
    const char* Ac = (const char*)A;
    const char* Wc = (const char*)Wb;
    char* ldsA = (char*)lA;
    char* ldsB = (char*)lB;
    const int swzR = (quad ^ ((l16 >> 1) & 3)) * 16;     // frag-read chunk XOR

    for (int kk = 0; kk < K; kk += 32) {
        __syncthreads();
        size_t ka = (SRC == SRC_HEADMAJ) ? (size_t)(kk >> 5) * 3136 : (size_t)kk * 2;
        size_t kb = (size_t)kk * 2;
#pragma unroll
        for (int s = 0; s < 2; s++)
            gll16(Ac + agb[s] + ka, ldsA + (wave * 2 + s) * 1024);
#pragma unroll
        for (int s = 0; s < 2; s++)
            gll16(Wc + wgb[s] + kb, ldsB + (wave * 2 + s) * 1024);
        __syncthreads();
        bf16x8 af[4], bfr[4];
#pragma unroll
        for (int t = 0; t < 4; t++)
            af[t] = *(const bf16x8*)(ldsA + (wm + t * 16 + l16) * 64 + swzR);
#pragma unroll
        for (int t = 0; t < 4; t++)
            bfr[t] = *(const bf16x8*)(ldsB + (wn + t * 16 + l16) * 64 + swzR);
#pragma unroll
        for (int i = 0; i < 4; i++)
#pragma unroll
            for (int j = 0; j < 4; j++)
                acc[i][j] = __builtin_amdgcn_mfma_f32_16x16x32_bf16(af[i], bfr[j], acc[i][j], 0, 0, 0);
    }

#pragma unroll
    for (int i = 0; i < 4; i++) {
#pragma unroll
        for (int r = 0; r < 4; r++) {
            int row = m0 + wm + i * 16 + quad * 4 + r;  // token index (window order / local)
            int widx = 0, n = 0;
            size_t pbase = 0;
            if (EPI == EPI_QKV || EPI == EPI_PROJ) { widx = row / 49; n = row % 49; }
            if (EPI == EPI_PROJ) {
                int bb = widx >> 6, wi = widx & 63;
                int hs = (wi >> 3) * 7 + n / 7, wsr = (wi & 7) * 7 + n % 7;
                int h = hs + 3; if (h >= 56) h -= 56;
                int w = wsr + 3; if (w >= 56) w -= 56;
                pbase = (((size_t)bb * 56 + h) * 56 + w) * 384;
            }
#pragma unroll
            for (int j = 0; j < 4; j++) {
                int col = n0 + wn + j * 16 + l16;
                float v = acc[i][j][r] + bias[col];
                if (EPI == EPI_QKV) {
                    int which = col / 384, head = (col >> 5) % 12, hd = col & 31;
                    u16* dst = (which == 0) ? o0 : ((which == 1) ? o1 : o2);
                    dst[(size_t)(widx * 12 + head) * 1568 + n * 32 + hd] = f2b(v);
                } else if (EPI == EPI_PROJ) {
                    dout[pbase + col] = v + xres[pbase + col];
                } else if (EPI == EPI_MLP1) {
                    float ge = 0.5f * v * (1.0f + erff(v * 0.70710678f));
                    o0[(size_t)row * 768 + col] = f2b(ge);
                } else {  // MLP2: dout += v
                    size_t o = (size_t)row * 384 + col;
                    dout[o] = v + dout[o];
                }
            }
        }
    }
}

// ---------------- Attention: MFMA, one wave per (window, head), barrier-free ----------------
__global__ __launch_bounds__(256)
void attn_mfma_kernel(const u16* __restrict__ q, const u16* __restrict__ k,
                      const u16* __restrict__ v, const float* __restrict__ rpb,
                      const float* __restrict__ mask, const float* __restrict__ lsc,
                      u16* __restrict__ out) {
    __shared__ alignas(16) u16 sP[4][64 * 72];   // P, stride 72 bf16 (144B, 16B-aligned)
    __shared__ alignas(16) u16 sVT[4][32 * 72];  // V^T [d][j], zero-padded j>=49
    __shared__ float sQin[4][64], sKin[4][64];   // per-row inv norms
    const int tid = threadIdx.x;
    const int wave = tid >> 6, lane = tid & 63;
    const int quad = lane >> 4, l16 = lane & 15;
    const int unit = blockIdx.x * 4 + wave;      // widx*12 + head
    const int widx = unit / 12, head = unit - widx * 12;
    const size_t base = (size_t)unit * 1568;
    u16* pP  = sP[wave];
    u16* pVT = sVT[wave];
    float* qin = sQin[wave];
    float* kin = sKin[wave];

    if (lane >= 49) { qin[lane] = 0.0f; kin[lane] = 0.0f; }

    // ---- stage V^T into LDS (cols 49..63 exactly zero) ----
    {
        const bool valid = lane < 49;
#pragma unroll
        for (int c = 0; c < 4; c++) {
            u16 r8[8] = {0, 0, 0, 0, 0, 0, 0, 0};
            if (valid) *(int4*)r8 = *(const int4*)&v[base + lane * 32 + c * 8];
#pragma unroll
            for (int e = 0; e < 8; e++) pVT[(c * 8 + e) * 72 + lane] = r8[e];
        }
    }

    // ---- load raw Q/K fragments + compute row inv-norms ----
    const float lscale = __expf(fminf(lsc[head], 4.6051702f));
    bf16x8 qf[4], kf[4];
#pragma unroll
    for (int t = 0; t < 4; t++) {
        int row = t * 16 + l16; if (row > 48) row = 48;   // duplicate last row into padding
        int4 qa = *(const int4*)&q[base + row * 32 + quad * 8];
        int4 ka = *(const int4*)&k[base + row * 32 + quad * 8];
        u16 qu[8], ku[8];
        *(int4*)qu = qa; *(int4*)ku = ka;
        float qs2 = 0.f, ks2 = 0.f;
#pragma unroll
        for (int e = 0; e < 8; e++) {
            float a = b2f(qu[e]), b = b2f(ku[e]);
            qs2 = fmaf(a, a, qs2); ks2 = fmaf(b, b, ks2);
        }
        qs2 += __shfl_xor(qs2, 16, 64); qs2 += __shfl_xor(qs2, 32, 64);
        ks2 += __shfl_xor(ks2, 16, 64); ks2 += __shfl_xor(ks2, 32, 64);
        if (quad == 0) {
            qin[row] = lscale * rsqrtf(fmaxf(qs2, 1e-24f));
            kin[row] = rsqrtf(fmaxf(ks2, 1e-24f));
        }
        qf[t] = *(bf16x8*)&qa;
        kf[t] = *(bf16x8*)&ka;
    }

    // ---- S = Q · K^T (64x64 padded), f32 accum ----
    f32x4 s[4][4] = {};
#pragma unroll
    for (int mi = 0; mi < 4; mi++)
#pragma unroll
        for (int ni = 0; ni < 4; ni++)
            s[mi][ni] = __builtin_amdgcn_mfma_f32_16x16x32_bf16(qf[mi], kf[ni], s[mi][ni], 0, 0, 0);

    // ---- softmax rows ----
    const float* rp = rpb + (size_t)head * 2401;
    const float* mk = mask + (size_t)(widx & 63) * 2401;
    float kj[4];
#pragma unroll
    for (int ni = 0; ni < 4; ni++) kj[ni] = kin[ni * 16 + l16];
#pragma unroll
    for (int mi = 0; mi < 4; mi++) {
#pragma unroll
        for (int r = 0; r < 4; r++) {
            const int i = mi * 16 + quad * 4 + r;       // D layout: row = quad*4+reg
            const float qi = qin[i];                    // 0 for padded rows
            const int ic = (i < 49 ? i : 48) * 49;
            const float* brow = rp + ic;
            const float* mrow = mk + ic;
            float lg[4];
#pragma unroll
            for (int ni = 0; ni < 4; ni++) {
                const int j = ni * 16 + l16;            // D layout: col = l16
                lg[ni] = (j < 49) ? fmaf(s[mi][ni][r], qi * kj[ni], brow[j] + mrow[j]) : -1e30f;
            }
            float m = fmaxf(fmaxf(lg[0], lg[1]), fmaxf(lg[2], lg[3]));
            m = fmaxf(m, __shfl_xor(m, 1, 64));
            m = fmaxf(m, __shfl_xor(m, 2, 64));
            m = fmaxf(m, __shfl_xor(m, 4, 64));
            m = fmaxf(m, __shfl_xor(m, 8, 64));
            float p0 = __expf(lg[0] - m), p1 = __expf(lg[1] - m);
            float p2 = __expf(lg[2] - m), p3 = __expf(lg[3] - m);
            float sum = p0 + p1 + p2 + p3;
            sum += __shfl_xor(sum, 1, 64);
            sum += __shfl_xor(sum, 2, 64);
            sum += __shfl_xor(sum, 4, 64);
            sum += __shfl_xor(sum, 8, 64);
            const float inv = 1.0f / sum;
            pP[i * 72 +  0 + l16] = f2b(p0 * inv);
            pP[i * 72 + 16 + l16] = f2b(p1 * inv);
            pP[i * 72 + 32 + l16] = f2b(p2 * inv);
            pP[i * 72 + 48 + l16] = f2b(p3 * inv);
        }
    }

    // ---- O = P · V ----
    bf16x8 vf[2][2];
#pragma unroll
    for (int kk = 0; kk < 2; kk++)
#pragma unroll
        for (int ni = 0; ni < 2; ni++)
            vf[kk][ni] = *(const bf16x8*)&pVT[(ni * 16 + l16) * 72 + kk * 32 + quad * 8];
    f32x4 o[4][2] = {};
#pragma unroll
    for (int mi = 0; mi < 4; mi++)
#pragma unroll
        for (int kk = 0; kk < 2; kk++) {
            bf16x8 pa = *(const bf16x8*)&pP[(mi * 16 + l16) * 72 + kk * 32 + quad * 8];
#pragma unroll
            for (int ni = 0; ni < 2; ni++)
                o[mi][ni] = __builtin_amdgcn_mfma_f32_16x16x32_bf16(pa, vf[kk][ni], o[mi][ni], 0, 0, 0);
        }

    // ---- write O (head-major layout, in-place over q slice) ----
#pragma unroll
    for (int mi = 0; mi < 4; mi++)
#pragma unroll
        for (int r = 0; r < 4; r++) {
            const int i = mi * 16 + quad * 4 + r;
            if (i < 49) {
                out[base + i * 32 + l16]      = f2b(o[mi][0][r]);
                out[base + i * 32 + 16 + l16] = f2b(o[mi][1][r]);
            }
        }
}

// ---------------- launch ----------------
extern "C" void kernel_launch(void* const* d_in, const int* in_sizes, int n_in,
                              void* d_out, int out_size, void* d_ws, size_t ws_size,
                              hipStream_t stream) {
    const float* x      = (const float*)d_in[0];
    const float* mask   = (const float*)d_in[1];
    const float* n1g    = (const float*)d_in[2];
    const float* n1b    = (const float*)d_in[3];
    const float* qkv_w  = (const float*)d_in[4];
    const float* qkv_b  = (const float*)d_in[5];
    const float* proj_w = (const float*)d_in[6];
    const float* proj_b = (const float*)d_in[7];
    const float* cpb_w1 = (const float*)d_in[8];
    const float* cpb_b1 = (const float*)d_in[9];
    const float* cpb_w2 = (const float*)d_in[10];
    const float* lscale = (const float*)d_in[11];
    const float* n2g    = (const float*)d_in[12];
    const float* n2b    = (const float*)d_in[13];
    const float* mlp_w1 = (const float*)d_in[14];
    const float* mlp_b1 = (const float*)d_in[15];
    const float* mlp_w2 = (const float*)d_in[16];
    const float* mlp_b2 = (const float*)d_in[17];

    char* ws = (char*)d_ws;
    const size_t SLOT = 77070336ULL;       // 100352*384*2 bytes (bf16 slot)
    float* tab = (float*)(ws);                     // 8112 B
    float* rpb = (float*)(ws + 16384);             // 115248 B
    u16*  Wb   = (u16*)(ws + (1 << 20));           // 2.36 MB bf16 weights (4 matrices)
    u16*  qkv_wb  = Wb;                            // 442368 el
    u16*  proj_wb = Wb + 442368;                   // 147456 el
    u16*  mlp1_wb = Wb + 589824;                   // 294912 el
    u16*  mlp2_wb = Wb + 884736;                   // 294912 el
    u16* qb = (u16*)(ws + (4 << 20));
    u16* kb = (u16*)(ws + (4 << 20) + SLOT);
    u16* vb = (u16*)d_out;                         // bf16 V staged in d_out[0:SLOT]
    u16* xb = (u16*)((char*)d_out + SLOT);         // LN1 bf16 (window rows) in d_out[SLOT:2*SLOT]
    u16* attn_o = qb;                              // attention writes in-place over q slices
    u16* xb2    = kb;                              // LN2 bf16 (raster rows), kb dead post-attn
    u16* hidden = qb;                              // per-half MLP hidden (50176*768*2 = SLOT)
    float* dout = (float*)d_out;
    // peak ws usage: 4 MB + 2*SLOT ~= 158 MB (unchanged)

    wconv_kernel<<<1152, 256, 0, stream>>>(qkv_w, proj_w, mlp_w1, mlp_w2, Wb);
    cpb_tab_kernel<<<169, 512, 0, stream>>>(cpb_w1, cpb_b1, cpb_w2, tab);
    cpb_gather_kernel<<<113, 256, 0, stream>>>(tab, rpb);
    ln_fused_kernel<1><<<25088, 256, 0, stream>>>(x, n1g, n1b, xb);
    gemm_mfma<SRC_PLAIN, EPI_QKV, 9><<<7056, 256, 0, stream>>>(
        xb, qkv_wb, qkv_b, 384, qb, kb, vb, nullptr, nullptr);
    attn_mfma_kernel<<<6144, 256, 0, stream>>>(qb, kb, vb, rpb, mask, lscale, attn_o);
    gemm_mfma<SRC_HEADMAJ, EPI_PROJ, 3><<<2352, 256, 0, stream>>>(
        attn_o, proj_wb, proj_b, 384, nullptr, nullptr, nullptr, x, dout);
    ln_fused_kernel<0><<<25088, 256, 0, stream>>>(dout, n2g, n2b, xb2);
    for (int h = 0; h < 2; h++) {
        gemm_mfma<SRC_PLAIN, EPI_MLP1, 6><<<2352, 256, 0, stream>>>(
            xb2 + (size_t)h * 50176 * 384, mlp1_wb, mlp_b1, 384,
            hidden, nullptr, nullptr, nullptr, nullptr);
        gemm_mfma<SRC_PLAIN, EPI_MLP2, 3><<<1176, 256, 0, stream>>>(
            hidden, mlp2_wb, mlp_b2, 768, nullptr, nullptr, nullptr,
            nullptr, dout + (size_t)h * 50176 * 384);
    }
}

// Round 4
// 1079.185 us; speedup vs baseline: 1.5953x; 1.0362x over previous
//
#include <hip/hip_runtime.h>
#include <stdint.h>

typedef unsigned short u16;
typedef __bf16 bf16x8 __attribute__((ext_vector_type(8)));
typedef float f32x4 __attribute__((ext_vector_type(4)));

__device__ __forceinline__ float b2f(u16 u) {
    union { float f; uint32_t i; } x; x.i = ((uint32_t)u) << 16; return x.f;
}
__device__ __forceinline__ u16 f2b(float f) {
    union { float f; uint32_t i; } x; x.f = f;
    uint32_t r = (x.i + 0x7fffu + ((x.i >> 16) & 1u)) >> 16;
    return (u16)r;
}
__device__ __forceinline__ void gll16(const void* g, void* l) {
    __builtin_amdgcn_global_load_lds((const __attribute__((address_space(1))) void*)g,
                                     (__attribute__((address_space(3))) void*)l, 16, 0, 0);
}

// ---------------- CPB: tab = relu(rel @ W1^T + b1) @ W2^T ----------------
__global__ __launch_bounds__(512)
void cpb_tab_kernel(const float* __restrict__ w1, const float* __restrict__ b1,
                    const float* __restrict__ w2, float* __restrict__ tab) {
    __shared__ float hbuf[512];
    int p = blockIdx.x, j = threadIdx.x;
    int i0 = p / 13, i1 = p % 13;
    float c0 = (i0 - 6) * (8.0f / 6.0f), c1 = (i1 - 6) * (8.0f / 6.0f);
    float r0 = copysignf(log2f(fabsf(c0) + 1.0f) * (1.0f / 3.0f), c0);
    float r1 = copysignf(log2f(fabsf(c1) + 1.0f) * (1.0f / 3.0f), c1);
    float h = r0 * w1[j * 2] + r1 * w1[j * 2 + 1] + b1[j];
    hbuf[j] = fmaxf(h, 0.0f);
    __syncthreads();
    if (j < 12) {
        float s = 0.0f;
        for (int t = 0; t < 512; t++) s += w2[j * 512 + t] * hbuf[t];
        tab[p * 12 + j] = s;
    }
}

__global__ __launch_bounds__(256)
void cpb_gather_kernel(const float* __restrict__ tab, float* __restrict__ rpb) {
    int idx = blockIdx.x * 256 + threadIdx.x;
    if (idx >= 12 * 2401) return;
    int h = idx / 2401, r = idx % 2401, i = r / 49, j = r % 49;
    int d = (i / 7 - j / 7 + 6) * 13 + (i % 7 - j % 7 + 6);
    float v = tab[d * 12 + h];
    rpb[idx] = 16.0f / (1.0f + expf(-v));
}

// ---------------- weights fp32 -> bf16, all four matrices packed ----------------
__global__ __launch_bounds__(256)
void wconv_kernel(const float* __restrict__ s0, const float* __restrict__ s1,
                  const float* __restrict__ s2, const float* __restrict__ s3,
                  u16* __restrict__ dst) {
    int i = (blockIdx.x * 256 + threadIdx.x) * 4;
    if (i >= 1179648) return;
    const float* src; int off;
    if (i < 442368)      { src = s0; off = i; }
    else if (i < 589824) { src = s1; off = i - 442368; }
    else if (i < 884736) { src = s2; off = i - 589824; }
    else                 { src = s3; off = i - 884736; }
    float4 v = *(const float4*)(src + off);
    u16 o[4] = {f2b(v.x), f2b(v.y), f2b(v.z), f2b(v.w)};
    *(uint2*)(dst + i) = *(const uint2*)o;
}

// ---------------- fused LN: stats + apply + bf16 write (PERM: shifted-window rows) ----------------
template <int PERM>
__global__ __launch_bounds__(256)
void ln_fused_kernel(const float* __restrict__ in, const float* __restrict__ g,
                     const float* __restrict__ b, u16* __restrict__ outb) {
    int wave = threadIdx.x >> 6, lane = threadIdx.x & 63;
    int tok = blockIdx.x * 4 + wave;
    size_t src = (size_t)tok * 384;
    float2 v[3];
    float s = 0.0f, s2 = 0.0f;
#pragma unroll
    for (int i = 0; i < 3; i++) {
        v[i] = *(const float2*)&in[src + i * 128 + lane * 2];
        s += v[i].x + v[i].y;
        s2 += v[i].x * v[i].x + v[i].y * v[i].y;
    }
#pragma unroll
    for (int m = 32; m >= 1; m >>= 1) { s += __shfl_xor(s, m, 64); s2 += __shfl_xor(s2, m, 64); }
    float mu = s * (1.0f / 384.0f);
    float rstd = rsqrtf(s2 * (1.0f / 384.0f) - mu * mu + 1e-5f);
    int drow = tok;
    if (PERM) {
        int bb = tok / 3136, rr = tok % 3136;
        int h = rr / 56, w = rr % 56;
        int hs = h - 3; if (hs < 0) hs += 56;
        int wsr = w - 3; if (wsr < 0) wsr += 56;
        int wi = (hs / 7) * 8 + (wsr / 7);
        int n = (hs % 7) * 7 + (wsr % 7);
        drow = (bb * 64 + wi) * 49 + n;
    }
    size_t dst = (size_t)drow * 384;
#pragma unroll
    for (int i = 0; i < 3; i++) {
        int c = i * 128 + lane * 2;
        float2 gg = *(const float2*)&g[c];
        float2 bv = *(const float2*)&b[c];
        u16 o[2] = { f2b((v[i].x - mu) * rstd * gg.x + bv.x),
                     f2b((v[i].y - mu) * rstd * gg.y + bv.y) };
        *(uint32_t*)&outb[dst + c] = *(const uint32_t*)o;
    }
}

// ---------------- MFMA GEMM: double-buffered global_load_lds pipeline ----------------
// LDS tile [128][32] bf16 linear (64B rows), 2 buffers each for A and B.
// Per step: STAGE(next) issued BEFORE compute(cur); single barrier per step
// (its vmcnt(0) drain lands AFTER MFMA, so load latency overlaps compute).
// Both-sides XOR swizzle (rule 21): linear LDS dest, inverse-swizzled global
// source chunk, same XOR on frag reads. XCD-chunked block swizzle (nwg%8==0).
enum { SRC_PLAIN = 0, SRC_HEADMAJ = 1 };
enum { EPI_QKV = 0, EPI_PROJ = 1, EPI_MLP1 = 2, EPI_MLP2 = 3 };

template <int SRC, int EPI, int GX, int K>
__global__ __launch_bounds__(256, 3)
void gemm_mfma(const u16* __restrict__ A, const u16* __restrict__ Wb,
               const float* __restrict__ bias,
               u16* __restrict__ o0, u16* __restrict__ o1, u16* __restrict__ o2,
               const float* __restrict__ xres, float* __restrict__ dout) {
    const int tid = threadIdx.x;
    const int wave = tid >> 6, lane = tid & 63, quad = lane >> 4, l16 = lane & 15;
    const int wm = (wave >> 1) * 64, wn = (wave & 1) * 64;
    // XCD-chunked bijective remap (consecutive nb on one XCD)
    const int bid = blockIdx.x;
    const int nb = (bid & 7) * ((int)gridDim.x >> 3) + (bid >> 3);
    const int m0 = (nb / GX) * 128, n0 = (nb % GX) * 128;
    __shared__ alignas(16) u16 lA[2][128 * 32];
    __shared__ alignas(16) u16 lB[2][128 * 32];
    f32x4 acc[4][4] = {};

    // staging: per thread, 2 issues per matrix; issue s covers LDS rows (wave*2+s)*16 + (lane>>2)
    const int c4 = lane & 3, rsub = lane >> 2;
    size_t agb[2], wgb[2];
#pragma unroll
    for (int s = 0; s < 2; s++) {
        int row = (wave * 2 + s) * 16 + rsub;           // 0..127
        int swz = (c4 ^ ((row >> 1) & 3)) * 16;          // byte chunk, inverse-swizzled
        int grow = m0 + row;
        if (SRC == SRC_HEADMAJ) {
            int widx = grow / 49, n = grow % 49;
            agb[s] = ((size_t)widx * 18816 + (size_t)n * 32) * 2 + swz;
        } else {
            agb[s] = (size_t)grow * (size_t)K * 2 + swz;
        }
        wgb[s] = (size_t)(n0 + row) * (size_t)K * 2 + swz;
    }
    const char* Ac = (const char*)A;
    const char* Wc = (const char*)Wb;
    const int swzR = (quad ^ ((l16 >> 1) & 3)) * 16;     // frag-read chunk XOR
    const int ldso = wave * 2048;                        // bytes: (wave*2)*1024

#define STAGE(buf, step)                                                        \
    {                                                                           \
        size_t ka = (SRC == SRC_HEADMAJ) ? (size_t)(step) * 3136                \
                                         : (size_t)(step) * 64;                 \
        size_t kb = (size_t)(step) * 64;                                        \
        char* la = (char*)lA[buf] + ldso;                                       \
        char* lb = (char*)lB[buf] + ldso;                                       \
        gll16(Ac + agb[0] + ka, la);                                            \
        gll16(Ac + agb[1] + ka, la + 1024);                                     \
        gll16(Wc + wgb[0] + kb, lb);                                            \
        gll16(Wc + wgb[1] + kb, lb + 1024);                                     \
    }

    constexpr int NSTEP = K / 32;
    STAGE(0, 0);
    __syncthreads();                                     // drains prologue vmcnt
#pragma unroll
    for (int step = 0; step < NSTEP; step++) {
        const int cur = step & 1;
        if (step + 1 < NSTEP) STAGE(cur ^ 1, step + 1);  // prefetch overlaps compute
        const char* la = (const char*)lA[cur];
        const char* lb = (const char*)lB[cur];
        bf16x8 af[4], bfr[4];
#pragma unroll
        for (int t = 0; t < 4; t++)
            af[t] = *(const bf16x8*)(la + (wm + t * 16 + l16) * 64 + swzR);
#pragma unroll
        for (int t = 0; t < 4; t++)
            bfr[t] = *(const bf16x8*)(lb + (wn + t * 16 + l16) * 64 + swzR);
#pragma unroll
        for (int i = 0; i < 4; i++)
#pragma unroll
            for (int j = 0; j < 4; j++)
                acc[i][j] = __builtin_amdgcn_mfma_f32_16x16x32_bf16(af[i], bfr[j], acc[i][j], 0, 0, 0);
        if (step + 1 < NSTEP) __syncthreads();           // one barrier per step
    }
#undef STAGE

#pragma unroll
    for (int i = 0; i < 4; i++) {
#pragma unroll
        for (int r = 0; r < 4; r++) {
            int row = m0 + wm + i * 16 + quad * 4 + r;  // token index (window order / local)
            int widx = 0, n = 0;
            size_t pbase = 0;
            if (EPI == EPI_QKV || EPI == EPI_PROJ) { widx = row / 49; n = row % 49; }
            if (EPI == EPI_PROJ) {
                int bb = widx >> 6, wi = widx & 63;
                int hs = (wi >> 3) * 7 + n / 7, wsr = (wi & 7) * 7 + n % 7;
                int h = hs + 3; if (h >= 56) h -= 56;
                int w = wsr + 3; if (w >= 56) w -= 56;
                pbase = (((size_t)bb * 56 + h) * 56 + w) * 384;
            }
#pragma unroll
            for (int j = 0; j < 4; j++) {
                int col = n0 + wn + j * 16 + l16;
                float v = acc[i][j][r] + bias[col];
                if (EPI == EPI_QKV) {
                    int which = col / 384, head = (col >> 5) % 12, hd = col & 31;
                    u16* dst = (which == 0) ? o0 : ((which == 1) ? o1 : o2);
                    dst[(size_t)(widx * 12 + head) * 1568 + n * 32 + hd] = f2b(v);
                } else if (EPI == EPI_PROJ) {
                    dout[pbase + col] = v + xres[pbase + col];
                } else if (EPI == EPI_MLP1) {
                    float ge = 0.5f * v * (1.0f + erff(v * 0.70710678f));
                    o0[(size_t)row * 768 + col] = f2b(ge);
                } else {  // MLP2: dout += v
                    size_t o = (size_t)row * 384 + col;
                    dout[o] = v + dout[o];
                }
            }
        }
    }
}

// ---------------- Attention: MFMA, one wave per (window, head), barrier-free ----------------
__global__ __launch_bounds__(256)
void attn_mfma_kernel(const u16* __restrict__ q, const u16* __restrict__ k,
                      const u16* __restrict__ v, const float* __restrict__ rpb,
                      const float* __restrict__ mask, const float* __restrict__ lsc,
                      u16* __restrict__ out) {
    __shared__ alignas(16) u16 sP[4][64 * 72];   // P, stride 72 bf16 (144B, 16B-aligned)
    __shared__ alignas(16) u16 sVT[4][32 * 72];  // V^T [d][j], zero-padded j>=49
    __shared__ float sQin[4][64], sKin[4][64];   // per-row inv norms
    const int tid = threadIdx.x;
    const int wave = tid >> 6, lane = tid & 63;
    const int quad = lane >> 4, l16 = lane & 15;
    const int unit = blockIdx.x * 4 + wave;      // widx*12 + head
    const int widx = unit / 12, head = unit - widx * 12;
    const size_t base = (size_t)unit * 1568;
    u16* pP  = sP[wave];
    u16* pVT = sVT[wave];
    float* qin = sQin[wave];
    float* kin = sKin[wave];

    if (lane >= 49) { qin[lane] = 0.0f; kin[lane] = 0.0f; }

    // ---- stage V^T into LDS (cols 49..63 exactly zero) ----
    {
        const bool valid = lane < 49;
#pragma unroll
        for (int c = 0; c < 4; c++) {
            u16 r8[8] = {0, 0, 0, 0, 0, 0, 0, 0};
            if (valid) *(int4*)r8 = *(const int4*)&v[base + lane * 32 + c * 8];
#pragma unroll
            for (int e = 0; e < 8; e++) pVT[(c * 8 + e) * 72 + lane] = r8[e];
        }
    }

    // ---- load raw Q/K fragments + compute row inv-norms ----
    const float lscale = __expf(fminf(lsc[head], 4.6051702f));
    bf16x8 qf[4], kf[4];
#pragma unroll
    for (int t = 0; t < 4; t++) {
        int row = t * 16 + l16; if (row > 48) row = 48;   // duplicate last row into padding
        int4 qa = *(const int4*)&q[base + row * 32 + quad * 8];
        int4 ka = *(const int4*)&k[base + row * 32 + quad * 8];
        u16 qu[8], ku[8];
        *(int4*)qu = qa; *(int4*)ku = ka;
        float qs2 = 0.f, ks2 = 0.f;
#pragma unroll
        for (int e = 0; e < 8; e++) {
            float a = b2f(qu[e]), b = b2f(ku[e]);
            qs2 = fmaf(a, a, qs2); ks2 = fmaf(b, b, ks2);
        }
        qs2 += __shfl_xor(qs2, 16, 64); qs2 += __shfl_xor(qs2, 32, 64);
        ks2 += __shfl_xor(ks2, 16, 64); ks2 += __shfl_xor(ks2, 32, 64);
        if (quad == 0) {
            qin[row] = lscale * rsqrtf(fmaxf(qs2, 1e-24f));
            kin[row] = rsqrtf(fmaxf(ks2, 1e-24f));
        }
        qf[t] = *(bf16x8*)&qa;
        kf[t] = *(bf16x8*)&ka;
    }

    // ---- S = Q · K^T (64x64 padded), f32 accum ----
    f32x4 s[4][4] = {};
    __builtin_amdgcn_s_setprio(1);
#pragma unroll
    for (int mi = 0; mi < 4; mi++)
#pragma unroll
        for (int ni = 0; ni < 4; ni++)
            s[mi][ni] = __builtin_amdgcn_mfma_f32_16x16x32_bf16(qf[mi], kf[ni], s[mi][ni], 0, 0, 0);
    __builtin_amdgcn_s_setprio(0);

    // ---- softmax rows ----
    const float* rp = rpb + (size_t)head * 2401;
    const float* mk = mask + (size_t)(widx & 63) * 2401;
    float kj[4];
#pragma unroll
    for (int ni = 0; ni < 4; ni++) kj[ni] = kin[ni * 16 + l16];
#pragma unroll
    for (int mi = 0; mi < 4; mi++) {
#pragma unroll
        for (int r = 0; r < 4; r++) {
            const int i = mi * 16 + quad * 4 + r;       // D layout: row = quad*4+reg
            const float qi = qin[i];                    // 0 for padded rows
            const int ic = (i < 49 ? i : 48) * 49;
            const float* brow = rp + ic;
            const float* mrow = mk + ic;
            float lg[4];
#pragma unroll
            for (int ni = 0; ni < 4; ni++) {
                const int j = ni * 16 + l16;            // D layout: col = l16
                lg[ni] = (j < 49) ? fmaf(s[mi][ni][r], qi * kj[ni], brow[j] + mrow[j]) : -1e30f;
            }
            float m = fmaxf(fmaxf(lg[0], lg[1]), fmaxf(lg[2], lg[3]));
            m = fmaxf(m, __shfl_xor(m, 1, 64));
            m = fmaxf(m, __shfl_xor(m, 2, 64));
            m = fmaxf(m, __shfl_xor(m, 4, 64));
            m = fmaxf(m, __shfl_xor(m, 8, 64));
            float p0 = __expf(lg[0] - m), p1 = __expf(lg[1] - m);
            float p2 = __expf(lg[2] - m), p3 = __expf(lg[3] - m);
            float sum = p0 + p1 + p2 + p3;
            sum += __shfl_xor(sum, 1, 64);
            sum += __shfl_xor(sum, 2, 64);
            sum += __shfl_xor(sum, 4, 64);
            sum += __shfl_xor(sum, 8, 64);
            const float inv = 1.0f / sum;
            pP[i * 72 +  0 + l16] = f2b(p0 * inv);
            pP[i * 72 + 16 + l16] = f2b(p1 * inv);
            pP[i * 72 + 32 + l16] = f2b(p2 * inv);
            pP[i * 72 + 48 + l16] = f2b(p3 * inv);
        }
    }

    // ---- O = P · V ----
    bf16x8 vf[2][2];
#pragma unroll
    for (int kk = 0; kk < 2; kk++)
#pragma unroll
        for (int ni = 0; ni < 2; ni++)
            vf[kk][ni] = *(const bf16x8*)&pVT[(ni * 16 + l16) * 72 + kk * 32 + quad * 8];
    f32x4 o[4][2] = {};
    __builtin_amdgcn_s_setprio(1);
#pragma unroll
    for (int mi = 0; mi < 4; mi++)
#pragma unroll
        for (int kk = 0; kk < 2; kk++) {
            bf16x8 pa = *(const bf16x8*)&pP[(mi * 16 + l16) * 72 + kk * 32 + quad * 8];
#pragma unroll
            for (int ni = 0; ni < 2; ni++)
                o[mi][ni] = __builtin_amdgcn_mfma_f32_16x16x32_bf16(pa, vf[kk][ni], o[mi][ni], 0, 0, 0);
        }
    __builtin_amdgcn_s_setprio(0);

    // ---- write O (head-major layout, in-place over q slice) ----
#pragma unroll
    for (int mi = 0; mi < 4; mi++)
#pragma unroll
        for (int r = 0; r < 4; r++) {
            const int i = mi * 16 + quad * 4 + r;
            if (i < 49) {
                out[base + i * 32 + l16]      = f2b(o[mi][0][r]);
                out[base + i * 32 + 16 + l16] = f2b(o[mi][1][r]);
            }
        }
}

// ---------------- launch ----------------
extern "C" void kernel_launch(void* const* d_in, const int* in_sizes, int n_in,
                              void* d_out, int out_size, void* d_ws, size_t ws_size,
                              hipStream_t stream) {
    const float* x      = (const float*)d_in[0];
    const float* mask   = (const float*)d_in[1];
    const float* n1g    = (const float*)d_in[2];
    const float* n1b    = (const float*)d_in[3];
    const float* qkv_w  = (const float*)d_in[4];
    const float* qkv_b  = (const float*)d_in[5];
    const float* proj_w = (const float*)d_in[6];
    const float* proj_b = (const float*)d_in[7];
    const float* cpb_w1 = (const float*)d_in[8];
    const float* cpb_b1 = (const float*)d_in[9];
    const float* cpb_w2 = (const float*)d_in[10];
    const float* lscale = (const float*)d_in[11];
    const float* n2g    = (const float*)d_in[12];
    const float* n2b    = (const float*)d_in[13];
    const float* mlp_w1 = (const float*)d_in[14];
    const float* mlp_b1 = (const float*)d_in[15];
    const float* mlp_w2 = (const float*)d_in[16];
    const float* mlp_b2 = (const float*)d_in[17];

    char* ws = (char*)d_ws;
    const size_t SLOT = 77070336ULL;       // 100352*384*2 bytes (bf16 slot)
    float* tab = (float*)(ws);                     // 8112 B
    float* rpb = (float*)(ws + 16384);             // 115248 B
    u16*  Wb   = (u16*)(ws + (1 << 20));           // 2.36 MB bf16 weights (4 matrices)
    u16*  qkv_wb  = Wb;                            // 442368 el
    u16*  proj_wb = Wb + 442368;                   // 147456 el
    u16*  mlp1_wb = Wb + 589824;                   // 294912 el
    u16*  mlp2_wb = Wb + 884736;                   // 294912 el
    u16* qb = (u16*)(ws + (4 << 20));
    u16* kb = (u16*)(ws + (4 << 20) + SLOT);
    u16* vb = (u16*)d_out;                         // bf16 V staged in d_out[0:SLOT]
    u16* xb = (u16*)((char*)d_out + SLOT);         // LN1 bf16 (window rows) in d_out[SLOT:2*SLOT]
    u16* attn_o = qb;                              // attention writes in-place over q slices
    u16* xb2    = kb;                              // LN2 bf16 (raster rows), kb dead post-attn
    u16* hidden = qb;                              // per-half MLP hidden (50176*768*2 = SLOT)
    float* dout = (float*)d_out;
    // peak ws usage: 4 MB + 2*SLOT ~= 158 MB (unchanged)

    wconv_kernel<<<1152, 256, 0, stream>>>(qkv_w, proj_w, mlp_w1, mlp_w2, Wb);
    cpb_tab_kernel<<<169, 512, 0, stream>>>(cpb_w1, cpb_b1, cpb_w2, tab);
    cpb_gather_kernel<<<113, 256, 0, stream>>>(tab, rpb);
    ln_fused_kernel<1><<<25088, 256, 0, stream>>>(x, n1g, n1b, xb);
    gemm_mfma<SRC_PLAIN, EPI_QKV, 9, 384><<<7056, 256, 0, stream>>>(
        xb, qkv_wb, qkv_b, qb, kb, vb, nullptr, nullptr);
    attn_mfma_kernel<<<6144, 256, 0, stream>>>(qb, kb, vb, rpb, mask, lscale, attn_o);
    gemm_mfma<SRC_HEADMAJ, EPI_PROJ, 3, 384><<<2352, 256, 0, stream>>>(
        attn_o, proj_wb, proj_b, nullptr, nullptr, nullptr, x, dout);
    ln_fused_kernel<0><<<25088, 256, 0, stream>>>(dout, n2g, n2b, xb2);
    for (int h = 0; h < 2; h++) {
        gemm_mfma<SRC_PLAIN, EPI_MLP1, 6, 384><<<2352, 256, 0, stream>>>(
            xb2 + (size_t)h * 50176 * 384, mlp1_wb, mlp_b1,
            hidden, nullptr, nullptr, nullptr, nullptr);
        gemm_mfma<SRC_PLAIN, EPI_MLP2, 3, 768><<<1176, 256, 0, stream>>>(
            hidden, mlp2_wb, mlp_b2, nullptr, nullptr, nullptr,
            nullptr, dout + (size_t)h * 50176 * 384);
    }
}

// Round 6
// 1026.789 us; speedup vs baseline: 1.6767x; 1.0510x over previous
//
#include <hip/hip_runtime.h>
#include <stdint.h>

typedef unsigned short u16;
typedef __bf16 bf16x8 __attribute__((ext_vector_type(8)));
typedef float f32x4 __attribute__((ext_vector_type(4)));

__device__ __forceinline__ float b2f(u16 u) {
    union { float f; uint32_t i; } x; x.i = ((uint32_t)u) << 16; return x.f;
}
__device__ __forceinline__ u16 f2b(float f) {
    union { float f; uint32_t i; } x; x.f = f;
    uint32_t r = (x.i + 0x7fffu + ((x.i >> 16) & 1u)) >> 16;
    return (u16)r;
}
__device__ __forceinline__ void gll16(const void* g, void* l) {
    __builtin_amdgcn_global_load_lds((const __attribute__((address_space(1))) void*)g,
                                     (__attribute__((address_space(3))) void*)l, 16, 0, 0);
}

// ---------------- CPB: tab = relu(rel @ W1^T + b1) @ W2^T ----------------
__global__ __launch_bounds__(512)
void cpb_tab_kernel(const float* __restrict__ w1, const float* __restrict__ b1,
                    const float* __restrict__ w2, float* __restrict__ tab) {
    __shared__ float hbuf[512];
    int p = blockIdx.x, j = threadIdx.x;
    int i0 = p / 13, i1 = p % 13;
    float c0 = (i0 - 6) * (8.0f / 6.0f), c1 = (i1 - 6) * (8.0f / 6.0f);
    float r0 = copysignf(log2f(fabsf(c0) + 1.0f) * (1.0f / 3.0f), c0);
    float r1 = copysignf(log2f(fabsf(c1) + 1.0f) * (1.0f / 3.0f), c1);
    float h = r0 * w1[j * 2] + r1 * w1[j * 2 + 1] + b1[j];
    hbuf[j] = fmaxf(h, 0.0f);
    __syncthreads();
    if (j < 12) {
        float s = 0.0f;
        for (int t = 0; t < 512; t++) s += w2[j * 512 + t] * hbuf[t];
        tab[p * 12 + j] = s;
    }
}

__global__ __launch_bounds__(256)
void cpb_gather_kernel(const float* __restrict__ tab, float* __restrict__ rpb) {
    int idx = blockIdx.x * 256 + threadIdx.x;
    if (idx >= 12 * 2401) return;
    int h = idx / 2401, r = idx % 2401, i = r / 49, j = r % 49;
    int d = (i / 7 - j / 7 + 6) * 13 + (i % 7 - j % 7 + 6);
    float v = tab[d * 12 + h];
    rpb[idx] = 16.0f / (1.0f + expf(-v));
}

// ---------------- combined bias: out[(w*12+h)*2401 + ij] = rpb[h] + mask[w] ----------------
__global__ __launch_bounds__(256)
void bias_combine_kernel(const float* __restrict__ rpb, const float* __restrict__ mask,
                         float* __restrict__ outb) {
    int idx = blockIdx.x * 256 + threadIdx.x;
    if (idx >= 768 * 2401) return;
    int wh = idx / 2401, ij = idx - wh * 2401;
    int w = wh / 12, h = wh - w * 12;
    outb[idx] = rpb[h * 2401 + ij] + mask[w * 2401 + ij];
}

// ---------------- weights fp32 -> bf16, all four matrices packed ----------------
__global__ __launch_bounds__(256)
void wconv_kernel(const float* __restrict__ s0, const float* __restrict__ s1,
                  const float* __restrict__ s2, const float* __restrict__ s3,
                  u16* __restrict__ dst) {
    int i = (blockIdx.x * 256 + threadIdx.x) * 4;
    if (i >= 1179648) return;
    const float* src; int off;
    if (i < 442368)      { src = s0; off = i; }
    else if (i < 589824) { src = s1; off = i - 442368; }
    else if (i < 884736) { src = s2; off = i - 589824; }
    else                 { src = s3; off = i - 884736; }
    float4 v = *(const float4*)(src + off);
    u16 o[4] = {f2b(v.x), f2b(v.y), f2b(v.z), f2b(v.w)};
    *(uint2*)(dst + i) = *(const uint2*)o;
}

// ---------------- fused LN: stats + apply + bf16 write (PERM: shifted-window rows) ----------------
template <int PERM>
__global__ __launch_bounds__(256)
void ln_fused_kernel(const float* __restrict__ in, const float* __restrict__ g,
                     const float* __restrict__ b, u16* __restrict__ outb) {
    int wave = threadIdx.x >> 6, lane = threadIdx.x & 63;
    int tok = blockIdx.x * 4 + wave;
    size_t src = (size_t)tok * 384;
    float2 v[3];
    float s = 0.0f, s2 = 0.0f;
#pragma unroll
    for (int i = 0; i < 3; i++) {
        v[i] = *(const float2*)&in[src + i * 128 + lane * 2];
        s += v[i].x + v[i].y;
        s2 += v[i].x * v[i].x + v[i].y * v[i].y;
    }
#pragma unroll
    for (int m = 32; m >= 1; m >>= 1) { s += __shfl_xor(s, m, 64); s2 += __shfl_xor(s2, m, 64); }
    float mu = s * (1.0f / 384.0f);
    float rstd = rsqrtf(s2 * (1.0f / 384.0f) - mu * mu + 1e-5f);
    int drow = tok;
    if (PERM) {
        int bb = tok / 3136, rr = tok % 3136;
        int h = rr / 56, w = rr % 56;
        int hs = h - 3; if (hs < 0) hs += 56;
        int wsr = w - 3; if (wsr < 0) wsr += 56;
        int wi = (hs / 7) * 8 + (wsr / 7);
        int n = (hs % 7) * 7 + (wsr % 7);
        drow = (bb * 64 + wi) * 49 + n;
    }
    size_t dst = (size_t)drow * 384;
#pragma unroll
    for (int i = 0; i < 3; i++) {
        int c = i * 128 + lane * 2;
        float2 gg = *(const float2*)&g[c];
        float2 bv = *(const float2*)&b[c];
        u16 o[2] = { f2b((v[i].x - mu) * rstd * gg.x + bv.x),
                     f2b((v[i].y - mu) * rstd * gg.y + bv.y) };
        *(uint32_t*)&outb[dst + c] = *(const uint32_t*)o;
    }
}

// ---------------- MFMA GEMM: double-buffered global_load_lds pipeline ----------------
enum { SRC_PLAIN = 0, SRC_HEADMAJ = 1 };
enum { EPI_QKV = 0, EPI_PROJ = 1, EPI_MLP1 = 2, EPI_MLP2 = 3 };

template <int SRC, int EPI, int GX, int K>
__global__ __launch_bounds__(256, 3)
void gemm_mfma(const u16* __restrict__ A, const u16* __restrict__ Wb,
               const float* __restrict__ bias,
               u16* __restrict__ o0, u16* __restrict__ o1, u16* __restrict__ o2,
               const float* __restrict__ xres, float* __restrict__ dout) {
    const int tid = threadIdx.x;
    const int wave = tid >> 6, lane = tid & 63, quad = lane >> 4, l16 = lane & 15;
    const int wm = (wave >> 1) * 64, wn = (wave & 1) * 64;
    const int bid = blockIdx.x;
    const int nb = (bid & 7) * ((int)gridDim.x >> 3) + (bid >> 3);
    const int m0 = (nb / GX) * 128, n0 = (nb % GX) * 128;
    __shared__ alignas(16) u16 lA[2][128 * 32];
    __shared__ alignas(16) u16 lB[2][128 * 32];
    f32x4 acc[4][4] = {};

    const int c4 = lane & 3, rsub = lane >> 2;
    size_t agb[2], wgb[2];
#pragma unroll
    for (int s = 0; s < 2; s++) {
        int row = (wave * 2 + s) * 16 + rsub;           // 0..127
        int swz = (c4 ^ ((row >> 1) & 3)) * 16;          // byte chunk, inverse-swizzled
        int grow = m0 + row;
        if (SRC == SRC_HEADMAJ) {
            int widx = grow / 49, n = grow % 49;
            agb[s] = ((size_t)widx * 18816 + (size_t)n * 32) * 2 + swz;
        } else {
            agb[s] = (size_t)grow * (size_t)K * 2 + swz;
        }
        wgb[s] = (size_t)(n0 + row) * (size_t)K * 2 + swz;
    }
    const char* Ac = (const char*)A;
    const char* Wc = (const char*)Wb;
    const int swzR = (quad ^ ((l16 >> 1) & 3)) * 16;     // frag-read chunk XOR
    const int ldso = wave * 2048;                        // bytes: (wave*2)*1024

#define STAGE(buf, step)                                                        \
    {                                                                           \
        size_t ka = (SRC == SRC_HEADMAJ) ? (size_t)(step) * 3136                \
                                         : (size_t)(step) * 64;                 \
        size_t kb = (size_t)(step) * 64;                                        \
        char* la = (char*)lA[buf] + ldso;                                       \
        char* lb = (char*)lB[buf] + ldso;                                       \
        gll16(Ac + agb[0] + ka, la);                                            \
        gll16(Ac + agb[1] + ka, la + 1024);                                     \
        gll16(Wc + wgb[0] + kb, lb);                                            \
        gll16(Wc + wgb[1] + kb, lb + 1024);                                     \
    }

    constexpr int NSTEP = K / 32;
    STAGE(0, 0);
    __syncthreads();
#pragma unroll
    for (int step = 0; step < NSTEP; step++) {
        const int cur = step & 1;
        if (step + 1 < NSTEP) STAGE(cur ^ 1, step + 1);
        const char* la = (const char*)lA[cur];
        const char* lb = (const char*)lB[cur];
        bf16x8 af[4], bfr[4];
#pragma unroll
        for (int t = 0; t < 4; t++)
            af[t] = *(const bf16x8*)(la + (wm + t * 16 + l16) * 64 + swzR);
#pragma unroll
        for (int t = 0; t < 4; t++)
            bfr[t] = *(const bf16x8*)(lb + (wn + t * 16 + l16) * 64 + swzR);
#pragma unroll
        for (int i = 0; i < 4; i++)
#pragma unroll
            for (int j = 0; j < 4; j++)
                acc[i][j] = __builtin_amdgcn_mfma_f32_16x16x32_bf16(af[i], bfr[j], acc[i][j], 0, 0, 0);
        if (step + 1 < NSTEP) __syncthreads();
    }
#undef STAGE

#pragma unroll
    for (int i = 0; i < 4; i++) {
#pragma unroll
        for (int r = 0; r < 4; r++) {
            int row = m0 + wm + i * 16 + quad * 4 + r;
            int widx = 0, n = 0;
            size_t pbase = 0;
            if (EPI == EPI_QKV || EPI == EPI_PROJ) { widx = row / 49; n = row % 49; }
            if (EPI == EPI_PROJ) {
                int bb = widx >> 6, wi = widx & 63;
                int hs = (wi >> 3) * 7 + n / 7, wsr = (wi & 7) * 7 + n % 7;
                int h = hs + 3; if (h >= 56) h -= 56;
                int w = wsr + 3; if (w >= 56) w -= 56;
                pbase = (((size_t)bb * 56 + h) * 56 + w) * 384;
            }
#pragma unroll
            for (int j = 0; j < 4; j++) {
                int col = n0 + wn + j * 16 + l16;
                float v = acc[i][j][r] + bias[col];
                if (EPI == EPI_QKV) {
                    int which = col / 384, head = (col >> 5) % 12, hd = col & 31;
                    u16* dst = (which == 0) ? o0 : ((which == 1) ? o1 : o2);
                    dst[(size_t)(widx * 12 + head) * 1568 + n * 32 + hd] = f2b(v);
                } else if (EPI == EPI_PROJ) {
                    dout[pbase + col] = v + xres[pbase + col];
                } else if (EPI == EPI_MLP1) {
                    float ge = 0.5f * v * (1.0f + erff(v * 0.70710678f));
                    o0[(size_t)row * 768 + col] = f2b(ge);
                } else {  // MLP2: dout += v
                    size_t o = (size_t)row * 384 + col;
                    dout[o] = v + dout[o];
                }
            }
        }
    }
}

// ---------------- Attention: MFMA, one wave per (window, head), barrier-free ----------------
// sP shrunk to 49 rows (junk rows never stored; PV row reads clamp to 48) ->
// 47.6 KB LDS/block -> 3 blocks/CU. Combined rpb+mask bias table halves the
// per-logit global loads.
__global__ __launch_bounds__(256)
void attn_mfma_kernel(const u16* __restrict__ q, const u16* __restrict__ k,
                      const u16* __restrict__ v, const float* __restrict__ biasc,
                      const float* __restrict__ lsc, u16* __restrict__ out) {
    __shared__ alignas(16) u16 sP[4][49 * 72];   // P rows 0..48, stride 72 bf16
    __shared__ alignas(16) u16 sVT[4][32 * 72];  // V^T [d][j], zero-padded j>=49
    __shared__ float sQin[4][64], sKin[4][64];   // per-row inv norms
    const int tid = threadIdx.x;
    const int wave = tid >> 6, lane = tid & 63;
    const int quad = lane >> 4, l16 = lane & 15;
    const int unit = blockIdx.x * 4 + wave;      // widx*12 + head
    const int widx = unit / 12, head = unit - widx * 12;
    const size_t base = (size_t)unit * 1568;
    u16* pP  = sP[wave];
    u16* pVT = sVT[wave];
    float* qin = sQin[wave];
    float* kin = sKin[wave];

    if (lane >= 49) { qin[lane] = 0.0f; kin[lane] = 0.0f; }

    // ---- stage V^T into LDS (cols 49..63 exactly zero) ----
    {
        const bool valid = lane < 49;
#pragma unroll
        for (int c = 0; c < 4; c++) {
            u16 r8[8] = {0, 0, 0, 0, 0, 0, 0, 0};
            if (valid) *(int4*)r8 = *(const int4*)&v[base + lane * 32 + c * 8];
#pragma unroll
            for (int e = 0; e < 8; e++) pVT[(c * 8 + e) * 72 + lane] = r8[e];
        }
    }

    // ---- load raw Q/K fragments + compute row inv-norms ----
    const float lscale = __expf(fminf(lsc[head], 4.6051702f));
    bf16x8 qf[4], kf[4];
#pragma unroll
    for (int t = 0; t < 4; t++) {
        int row = t * 16 + l16; if (row > 48) row = 48;   // duplicate last row into padding
        int4 qa = *(const int4*)&q[base + row * 32 + quad * 8];
        int4 ka = *(const int4*)&k[base + row * 32 + quad * 8];
        u16 qu[8], ku[8];
        *(int4*)qu = qa; *(int4*)ku = ka;
        float qs2 = 0.f, ks2 = 0.f;
#pragma unroll
        for (int e = 0; e < 8; e++) {
            float a = b2f(qu[e]), b = b2f(ku[e]);
            qs2 = fmaf(a, a, qs2); ks2 = fmaf(b, b, ks2);
        }
        qs2 += __shfl_xor(qs2, 16, 64); qs2 += __shfl_xor(qs2, 32, 64);
        ks2 += __shfl_xor(ks2, 16, 64); ks2 += __shfl_xor(ks2, 32, 64);
        if (quad == 0) {
            qin[row] = lscale * rsqrtf(fmaxf(qs2, 1e-24f));
            kin[row] = rsqrtf(fmaxf(ks2, 1e-24f));
        }
        qf[t] = *(bf16x8*)&qa;
        kf[t] = *(bf16x8*)&ka;
    }

    // ---- S = Q · K^T (64x64 padded), f32 accum ----
    f32x4 s[4][4] = {};
    __builtin_amdgcn_s_setprio(1);
#pragma unroll
    for (int mi = 0; mi < 4; mi++)
#pragma unroll
        for (int ni = 0; ni < 4; ni++)
            s[mi][ni] = __builtin_amdgcn_mfma_f32_16x16x32_bf16(qf[mi], kf[ni], s[mi][ni], 0, 0, 0);
    __builtin_amdgcn_s_setprio(0);

    // ---- softmax rows (combined bias; rows entirely >48 skipped) ----
    const float* bp = biasc + (size_t)((widx & 63) * 12 + head) * 2401;
    float kj[4];
#pragma unroll
    for (int ni = 0; ni < 4; ni++) kj[ni] = kin[ni * 16 + l16];
#pragma unroll
    for (int mi = 0; mi < 4; mi++) {
#pragma unroll
        for (int r = 0; r < 4; r++) {
            if (mi == 3 && r > 0) continue;             // i = 49.. for all quads
            const int i = mi * 16 + quad * 4 + r;       // D layout: row = quad*4+reg
            const float qi = qin[i];                    // 0 for padded rows
            const float* brow = bp + (i < 49 ? i : 48) * 49;
            float lg[4];
#pragma unroll
            for (int ni = 0; ni < 4; ni++) {
                const int j = ni * 16 + l16;            // D layout: col = l16
                lg[ni] = (j < 49) ? fmaf(s[mi][ni][r], qi * kj[ni], brow[j]) : -1e30f;
            }
            float m = fmaxf(fmaxf(lg[0], lg[1]), fmaxf(lg[2], lg[3]));
            m = fmaxf(m, __shfl_xor(m, 1, 64));
            m = fmaxf(m, __shfl_xor(m, 2, 64));
            m = fmaxf(m, __shfl_xor(m, 4, 64));
            m = fmaxf(m, __shfl_xor(m, 8, 64));
            float p0 = __expf(lg[0] - m), p1 = __expf(lg[1] - m);
            float p2 = __expf(lg[2] - m), p3 = __expf(lg[3] - m);
            float sum = p0 + p1 + p2 + p3;
            sum += __shfl_xor(sum, 1, 64);
            sum += __shfl_xor(sum, 2, 64);
            sum += __shfl_xor(sum, 4, 64);
            sum += __shfl_xor(sum, 8, 64);
            const float inv = 1.0f / sum;
            if (i < 49) {
                pP[i * 72 +  0 + l16] = f2b(p0 * inv);
                pP[i * 72 + 16 + l16] = f2b(p1 * inv);
                pP[i * 72 + 32 + l16] = f2b(p2 * inv);
                pP[i * 72 + 48 + l16] = f2b(p3 * inv);
            }
        }
    }

    // ---- O = P · V (P rows clamp to 48; clamped rows feed only unwritten outputs) ----
    bf16x8 vf[2][2];
#pragma unroll
    for (int kk = 0; kk < 2; kk++)
#pragma unroll
        for (int ni = 0; ni < 2; ni++)
            vf[kk][ni] = *(const bf16x8*)&pVT[(ni * 16 + l16) * 72 + kk * 32 + quad * 8];
    f32x4 o[4][2] = {};
    __builtin_amdgcn_s_setprio(1);
#pragma unroll
    for (int mi = 0; mi < 4; mi++) {
        int pr = mi * 16 + l16; if (pr > 48) pr = 48;
#pragma unroll
        for (int kk = 0; kk < 2; kk++) {
            bf16x8 pa = *(const bf16x8*)&pP[pr * 72 + kk * 32 + quad * 8];
#pragma unroll
            for (int ni = 0; ni < 2; ni++)
                o[mi][ni] = __builtin_amdgcn_mfma_f32_16x16x32_bf16(pa, vf[kk][ni], o[mi][ni], 0, 0, 0);
        }
    }
    __builtin_amdgcn_s_setprio(0);

    // ---- write O (head-major layout, in-place over q slice) ----
#pragma unroll
    for (int mi = 0; mi < 4; mi++)
#pragma unroll
        for (int r = 0; r < 4; r++) {
            const int i = mi * 16 + quad * 4 + r;
            if (i < 49) {
                out[base + i * 32 + l16]      = f2b(o[mi][0][r]);
                out[base + i * 32 + 16 + l16] = f2b(o[mi][1][r]);
            }
        }
}

// ---------------- launch ----------------
extern "C" void kernel_launch(void* const* d_in, const int* in_sizes, int n_in,
                              void* d_out, int out_size, void* d_ws, size_t ws_size,
                              hipStream_t stream) {
    const float* x      = (const float*)d_in[0];
    const float* mask   = (const float*)d_in[1];
    const float* n1g    = (const float*)d_in[2];
    const float* n1b    = (const float*)d_in[3];
    const float* qkv_w  = (const float*)d_in[4];
    const float* qkv_b  = (const float*)d_in[5];
    const float* proj_w = (const float*)d_in[6];
    const float* proj_b = (const float*)d_in[7];
    const float* cpb_w1 = (const float*)d_in[8];
    const float* cpb_b1 = (const float*)d_in[9];
    const float* cpb_w2 = (const float*)d_in[10];
    const float* lscale = (const float*)d_in[11];
    const float* n2g    = (const float*)d_in[12];
    const float* n2b    = (const float*)d_in[13];
    const float* mlp_w1 = (const float*)d_in[14];
    const float* mlp_b1 = (const float*)d_in[15];
    const float* mlp_w2 = (const float*)d_in[16];
    const float* mlp_b2 = (const float*)d_in[17];

    char* ws = (char*)d_ws;
    const size_t SLOT = 77070336ULL;       // 100352*384*2 bytes (bf16 slot)
    float* tab = (float*)(ws);                     // 8112 B
    float* rpb = (float*)(ws + 16384);             // 115248 B
    u16*  Wb   = (u16*)(ws + (1 << 20));           // 2.36 MB bf16 weights (4 matrices)
    u16*  qkv_wb  = Wb;                            // 442368 el
    u16*  proj_wb = Wb + 442368;                   // 147456 el
    u16*  mlp1_wb = Wb + 589824;                   // 294912 el
    u16*  mlp2_wb = Wb + 884736;                   // 294912 el
    u16* qb = (u16*)(ws + (4 << 20));
    u16* kb = (u16*)(ws + (4 << 20) + SLOT);
    u16* vb = (u16*)d_out;                         // bf16 V staged in d_out[0:SLOT]
    u16* xb = (u16*)((char*)d_out + SLOT);         // LN1 bf16 (window rows), dead after QKV
    float* biasc = (float*)((char*)d_out + SLOT);  // 7.4 MB combined bias, overwrites dead xb
    u16* attn_o = qb;                              // attention writes in-place over q slices
    u16* xb2    = kb;                              // LN2 bf16 (raster rows), kb dead post-attn
    u16* hidden = qb;                              // per-half MLP hidden (50176*768*2 = SLOT)
    float* dout = (float*)d_out;
    // peak ws usage: 4 MB + 2*SLOT ~= 158 MB (unchanged)

    wconv_kernel<<<1152, 256, 0, stream>>>(qkv_w, proj_w, mlp_w1, mlp_w2, Wb);
    cpb_tab_kernel<<<169, 512, 0, stream>>>(cpb_w1, cpb_b1, cpb_w2, tab);
    cpb_gather_kernel<<<113, 256, 0, stream>>>(tab, rpb);
    ln_fused_kernel<1><<<25088, 256, 0, stream>>>(x, n1g, n1b, xb);
    gemm_mfma<SRC_PLAIN, EPI_QKV, 9, 384><<<7056, 256, 0, stream>>>(
        xb, qkv_wb, qkv_b, qb, kb, vb, nullptr, nullptr);
    bias_combine_kernel<<<7203, 256, 0, stream>>>(rpb, mask, biasc);  // after QKV: xb dead
    attn_mfma_kernel<<<6144, 256, 0, stream>>>(qb, kb, vb, biasc, lscale, attn_o);
    gemm_mfma<SRC_HEADMAJ, EPI_PROJ, 3, 384><<<2352, 256, 0, stream>>>(
        attn_o, proj_wb, proj_b, nullptr, nullptr, nullptr, x, dout);
    ln_fused_kernel<0><<<25088, 256, 0, stream>>>(dout, n2g, n2b, xb2);
    for (int h = 0; h < 2; h++) {
        gemm_mfma<SRC_PLAIN, EPI_MLP1, 6, 384><<<2352, 256, 0, stream>>>(
            xb2 + (size_t)h * 50176 * 384, mlp1_wb, mlp_b1,
            hidden, nullptr, nullptr, nullptr, nullptr);
        gemm_mfma<SRC_PLAIN, EPI_MLP2, 3, 768><<<1176, 256, 0, stream>>>(
            hidden, mlp2_wb, mlp_b2, nullptr, nullptr, nullptr,
            nullptr, dout + (size_t)h * 50176 * 384);
    }
}